// Round 7
// baseline (270.672 us; speedup 1.0000x reference)
//
#include <hip/hip_runtime.h>
#include <hip/hip_bf16.h>

namespace {
constexpr int kB = 8;
constexpr int kC = 64;
constexpr int kH = 48;
constexpr int kW = 48;
constexpr int kS = kH * kW;          // 2304
constexpr float kEps = 1.1920929e-07f;
}

typedef __attribute__((ext_vector_type(8))) short short8;   // 8 bf16 (4 VGPR)
typedef __attribute__((ext_vector_type(4))) short short4_t; // 4 bf16 (2 VGPR)
typedef __attribute__((ext_vector_type(4))) float f32x4;

// fp32 -> bf16 (round-nearest-even), bit-level
__device__ __forceinline__ short f2bf(float x) {
  unsigned u = __float_as_uint(x);
  u += 0x7fffu + ((u >> 16) & 1u);
  return (short)(u >> 16);
}
__device__ __forceinline__ float bf2f(short s) {
  return __uint_as_float(((unsigned)(unsigned short)s) << 16);
}

// ---------------------------------------------------------------------------
// F1: fused prep.
//  blocks [0,576):    transpose q,k [b][c][s] fp32 -> [b][s][c] bf16
//  blocks [576,1728): v fp32 -> bf16 cast (same layout), 1024 elems/block
//  blocks [1728,1904): weight prep (wq,wk bf16; conv_w -> [tap][co][ci] bf16)
// ---------------------------------------------------------------------------
__global__ __launch_bounds__(256) void fused_prep(
    const float* __restrict__ q, const float* __restrict__ k,
    const float* __restrict__ v, const float* __restrict__ wq,
    const float* __restrict__ wk, const float* __restrict__ conv_w,
    short* __restrict__ qt, short* __restrict__ kt, short* __restrict__ vt,
    short* __restrict__ wqb, short* __restrict__ wkb, short* __restrict__ wt2) {
  const int blk = blockIdx.x;
  if (blk < 576) {
    __shared__ float tile[64][65];
    const int zz = blk / 36;         // b*2 + which
    const int bx = blk % 36;
    const int b = zz >> 1;
    const float* src = (zz & 1) ? k : q;
    short* dst = (zz & 1) ? kt : qt;
    const int s0 = bx * 64;
    const int tx = threadIdx.x & 63;
    const int ty = threadIdx.x >> 6;
#pragma unroll
    for (int r = 0; r < 16; ++r) {
      int c = r * 4 + ty;
      tile[c][tx] = src[((size_t)b * kC + c) * kS + s0 + tx];
    }
    __syncthreads();
#pragma unroll
    for (int r = 0; r < 16; ++r) {
      int s = r * 4 + ty;
      dst[((size_t)b * kS + s0 + s) * kC + tx] = f2bf(tile[tx][s]);
    }
  } else if (blk < 1728) {
    int idx = ((blk - 576) * 256 + threadIdx.x) * 4;
    float4 x = *reinterpret_cast<const float4*>(v + idx);
    int2 o;
    o.x = ((int)(unsigned short)f2bf(x.y) << 16) | (unsigned short)f2bf(x.x);
    o.y = ((int)(unsigned short)f2bf(x.w) << 16) | (unsigned short)f2bf(x.z);
    *reinterpret_cast<int2*>(vt + idx) = o;
  } else {
    int idx = (blk - 1728) * 256 + threadIdx.x;
    if (idx < 4096) {
      wqb[idx] = f2bf(wq[idx]);
    } else if (idx < 8192) {
      wkb[idx - 4096] = f2bf(wk[idx - 4096]);
    } else {
      int i = idx - 8192;
      int ci = i & 63, co = (i >> 6) & 63, tap = i >> 12;
      wt2[i] = f2bf(conv_w[co * 576 + ci * 9 + tap]);
    }
  }
}

// ---------------------------------------------------------------------------
// F2: fused q/k projection GEMMs.
//  blocks [0,288):   q path (conv 9-tap GEMM + RMSNorm + wq proj, *0.25)
//  blocks [288,576): k path (RMSNorm + wk proj)
// ---------------------------------------------------------------------------
__global__ __launch_bounds__(256) void fused_qk_gemm(
    const short* __restrict__ qt, const short* __restrict__ kt,
    const short* __restrict__ wt2, const short* __restrict__ wqb,
    const short* __restrict__ wkb,
    const float* __restrict__ nq_w, const float* __restrict__ nk_w,
    const float* __restrict__ bq, const float* __restrict__ bk,
    short* __restrict__ qp, short* __restrict__ kp) {
  __shared__ __align__(16) short ln[4][16][80];
  const int blk = blockIdx.x;
  const int t = threadIdx.x;
  const int ws = t >> 6;
  const int L = t & 63;
  const int quad = L >> 4;
  const int l16 = L & 15;
  const short8 zero8 = {0, 0, 0, 0, 0, 0, 0, 0};

  if (blk < 288) {
    // ---- q path ----
    const int b = blk / 36;
    const int sBase = (blk % 36) * 64 + ws * 16;
    const int s = sBase + l16;
    const int h = s / kW, w = s % kW;

    f32x4 acc[4] = {{0.f, 0.f, 0.f, 0.f}, {0.f, 0.f, 0.f, 0.f},
                    {0.f, 0.f, 0.f, 0.f}, {0.f, 0.f, 0.f, 0.f}};
#pragma unroll
    for (int tap = 0; tap < 9; ++tap) {
      const int dh = tap / 3 - 1, dw = tap % 3 - 1;
      const bool valid = (unsigned)(h + dh) < (unsigned)kH &&
                         (unsigned)(w + dw) < (unsigned)kW;
      const int srow = valid ? (s + dh * kW + dw) : s;
      const short8* ap = reinterpret_cast<const short8*>(
          qt + ((size_t)b * kS + srow) * kC);
#pragma unroll
      for (int kh = 0; kh < 2; ++kh) {
        short8 af = ap[kh * 4 + quad];
        af = valid ? af : zero8;
        const short* wb = wt2 + tap * 4096 + l16 * kC + kh * 32 + quad * 8;
#pragma unroll
        for (int nt = 0; nt < 4; ++nt) {
          short8 bf = *reinterpret_cast<const short8*>(wb + nt * 16 * kC);
          acc[nt] = __builtin_amdgcn_mfma_f32_16x16x32_bf16(af, bf, acc[nt], 0, 0, 0);
        }
      }
    }
    float rstd[4];
#pragma unroll
    for (int reg = 0; reg < 4; ++reg) {
      float pr = acc[0][reg] * acc[0][reg] + acc[1][reg] * acc[1][reg]
               + acc[2][reg] * acc[2][reg] + acc[3][reg] * acc[3][reg];
      pr += __shfl_xor(pr, 1, 64);
      pr += __shfl_xor(pr, 2, 64);
      pr += __shfl_xor(pr, 4, 64);
      pr += __shfl_xor(pr, 8, 64);
      rstd[reg] = rsqrtf(pr * (1.0f / kC) + kEps);
    }
#pragma unroll
    for (int nt = 0; nt < 4; ++nt) {
      float g = nq_w[nt * 16 + l16];
#pragma unroll
      for (int reg = 0; reg < 4; ++reg) {
        ln[ws][quad * 4 + reg][nt * 16 + l16] = f2bf(acc[nt][reg] * rstd[reg] * g);
      }
    }
    __syncthreads();
    f32x4 acc2[4] = {{0.f, 0.f, 0.f, 0.f}, {0.f, 0.f, 0.f, 0.f},
                     {0.f, 0.f, 0.f, 0.f}, {0.f, 0.f, 0.f, 0.f}};
#pragma unroll
    for (int kh = 0; kh < 2; ++kh) {
      short8 af = *reinterpret_cast<const short8*>(&ln[ws][l16][kh * 32 + quad * 8]);
#pragma unroll
      for (int nt = 0; nt < 4; ++nt) {
        short8 bf = *reinterpret_cast<const short8*>(
            wqb + (nt * 16 + l16) * kC + kh * 32 + quad * 8);
        acc2[nt] = __builtin_amdgcn_mfma_f32_16x16x32_bf16(af, bf, acc2[nt], 0, 0, 0);
      }
    }
#pragma unroll
    for (int nt = 0; nt < 4; ++nt) {
      const int e = nt * 16 + l16;
      float bias = bq[e];
#pragma unroll
      for (int reg = 0; reg < 4; ++reg) {
        qp[((size_t)b * kS + sBase + quad * 4 + reg) * kC + e] =
            f2bf((acc2[nt][reg] + bias) * 0.25f);
      }
    }
  } else {
    // ---- k path ----
    const int idx = blk - 288;
    const int b = idx / 36;
    const int sBase = (idx % 36) * 64 + ws * 16;
    const int s = sBase + l16;

    const short8* ap = reinterpret_cast<const short8*>(
        kt + ((size_t)b * kS + s) * kC);
    short8 af0 = ap[quad];
    short8 af1 = ap[4 + quad];

    float xs[16];
#pragma unroll
    for (int j = 0; j < 8; ++j) { xs[j] = bf2f(af0[j]); xs[8 + j] = bf2f(af1[j]); }
    float sum = 0.f;
#pragma unroll
    for (int j = 0; j < 16; ++j) sum = fmaf(xs[j], xs[j], sum);
    sum += __shfl_xor(sum, 16, 64);
    sum += __shfl_xor(sum, 32, 64);
    float rstd = rsqrtf(sum * (1.0f / kC) + kEps);

    const float* n0 = nk_w + quad * 8;
#pragma unroll
    for (int j = 0; j < 8; ++j) {
      af0[j] = f2bf(xs[j] * rstd * n0[j]);
      af1[j] = f2bf(xs[8 + j] * rstd * n0[32 + j]);
    }

    f32x4 acc[4] = {{0.f, 0.f, 0.f, 0.f}, {0.f, 0.f, 0.f, 0.f},
                    {0.f, 0.f, 0.f, 0.f}, {0.f, 0.f, 0.f, 0.f}};
#pragma unroll
    for (int nt = 0; nt < 4; ++nt) {
      short8 bf0 = *reinterpret_cast<const short8*>(
          wkb + (nt * 16 + l16) * kC + quad * 8);
      short8 bf1 = *reinterpret_cast<const short8*>(
          wkb + (nt * 16 + l16) * kC + 32 + quad * 8);
      acc[nt] = __builtin_amdgcn_mfma_f32_16x16x32_bf16(af0, bf0, acc[nt], 0, 0, 0);
      acc[nt] = __builtin_amdgcn_mfma_f32_16x16x32_bf16(af1, bf1, acc[nt], 0, 0, 0);
    }
#pragma unroll
    for (int nt = 0; nt < 4; ++nt) {
      const int e = nt * 16 + l16;
      float bias = bk[e];
#pragma unroll
      for (int reg = 0; reg < 4; ++reg) {
        kp[((size_t)b * kS + sBase + quad * 4 + reg) * kC + e] =
            f2bf(acc[nt][reg] + bias);
      }
    }
  }
}

// ---------------------------------------------------------------------------
// K3: single-pass barrier-free MFMA attention.
// grid (144, 8), 256 thr (4 waves). Wave ws owns j stripe {jt*64+ws*16+...}.
// Per 16-j chunk (K=16 MFMAs, head_dim=16 exactly):
//   S^T_h = mfma(A=K_h, B=Q_h)   -> lane: (j=quad*4+reg, i=l16)
//   e = exp(S^T)                 -> already B-operand layout (k=quad*4+idx)!
//   U_h[dvt] += mfma(A=V^T, B=P^T)  (per-head unnormalized output, O^T layout)
//   l_h(i)  += row sums
// No LDS / no barriers in the loop. Epilogue: cross-wave reduce of U via
// 4.3 KB LDS buffer; O = sum_h U_h * (0.25/l_h).
// ---------------------------------------------------------------------------
__global__ __launch_bounds__(256) void attn_mfma(
    const short* __restrict__ qp, const short* __restrict__ kp,
    const short* __restrict__ vt, float* __restrict__ out) {
  __shared__ float pl[4][16][4];     // per-wave l partials [ws][i][h]
  __shared__ float Li[16][4];        // 0.25 / l
  __shared__ float ubuf[4][16][17];  // [ws][dv_local][i]

  const int b = blockIdx.y;
  const int i0 = blockIdx.x * 16;
  const int t = threadIdx.x;
  const int ws = t >> 6;
  const int L = t & 63;
  const int quad = L >> 4;
  const int l16 = L & 15;

  const f32x4 zc = {0.f, 0.f, 0.f, 0.f};

  // Q fragments (B operand): head h dims h*16 + quad*4 .. +3 of row i0+l16
  const short* qrow = qp + ((size_t)b * kS + i0 + l16) * kC + quad * 4;
  short4_t qh[4];
#pragma unroll
  for (int h = 0; h < 4; ++h)
    qh[h] = *reinterpret_cast<const short4_t*>(qrow + h * 16);

  // K base: row j = jt*64 + ws*16 + l16, dims h*16 + quad*4
  const short* kbase = kp + ((size_t)b * kS + ws * 16 + l16) * kC + quad * 4;
  // V^T base (A operand): row dv = dvt*16 + l16, col j = jt*64 + ws*16 + quad*4
  const short* vbase = vt + ((size_t)b * kC + l16) * kS + ws * 16 + quad * 4;

  f32x4 U[4][4];   // [h][dvt], O^T fragments
#pragma unroll
  for (int h = 0; h < 4; ++h)
#pragma unroll
    for (int d = 0; d < 4; ++d) U[h][d] = zc;
  float lh[4] = {0.f, 0.f, 0.f, 0.f};

  for (int jt = 0; jt < kS / 64; ++jt) {
    const short* kr = kbase + (size_t)jt * 64 * kC;
    short4_t kf[4];
#pragma unroll
    for (int h = 0; h < 4; ++h)
      kf[h] = *reinterpret_cast<const short4_t*>(kr + h * 16);
    const short* vr = vbase + jt * 64;
    short4_t vf[4];
#pragma unroll
    for (int d = 0; d < 4; ++d)
      vf[d] = *reinterpret_cast<const short4_t*>(vr + (size_t)d * 16 * kS);

    short4_t p[4];
#pragma unroll
    for (int h = 0; h < 4; ++h) {
      f32x4 s = __builtin_amdgcn_mfma_f32_16x16x16bf16_1k(kf[h], qh[h], zc, 0, 0, 0);
      float e0 = __expf(s[0]), e1 = __expf(s[1]);
      float e2 = __expf(s[2]), e3 = __expf(s[3]);
      lh[h] += (e0 + e1) + (e2 + e3);
      union { __hip_bfloat162 h2[2]; short4_t s4; } cv;
      cv.h2[0] = __float22bfloat162_rn(make_float2(e0, e1));
      cv.h2[1] = __float22bfloat162_rn(make_float2(e2, e3));
      p[h] = cv.s4;
    }
#pragma unroll
    for (int h = 0; h < 4; ++h)
#pragma unroll
      for (int d = 0; d < 4; ++d)
        U[h][d] = __builtin_amdgcn_mfma_f32_16x16x16bf16_1k(vf[d], p[h], U[h][d], 0, 0, 0);
  }

  // ---- epilogue ----
  // reduce l over quads (lanes differing in bits 4,5 share i=l16)
#pragma unroll
  for (int h = 0; h < 4; ++h) {
    lh[h] += __shfl_xor(lh[h], 16, 64);
    lh[h] += __shfl_xor(lh[h], 32, 64);
  }
  if (quad == 0) {
#pragma unroll
    for (int h = 0; h < 4; ++h) pl[ws][l16][h] = lh[h];
  }
  __syncthreads();
  if (t < 64) {
    const int i = t >> 2, h = t & 3;
    Li[i][h] = 0.25f / (pl[0][i][h] + pl[1][i][h] + pl[2][i][h] + pl[3][i][h]);
  }
  __syncthreads();

  // cross-wave U reduce + head combine. thread t -> (i = t>>4, dv_local = t&15)
  const int em = t & 15;     // dv_local
  const int en = t >> 4;     // i
  float Of[4] = {0.f, 0.f, 0.f, 0.f};
#pragma unroll
  for (int dvt = 0; dvt < 4; ++dvt) {
#pragma unroll
    for (int h = 0; h < 4; ++h) {
#pragma unroll
      for (int r = 0; r < 4; ++r)
        ubuf[ws][quad * 4 + r][l16] = U[h][dvt][r];
      __syncthreads();
      float val = ubuf[0][em][en] + ubuf[1][em][en]
                + ubuf[2][em][en] + ubuf[3][em][en];
      Of[dvt] += val * Li[en][h];
      __syncthreads();
    }
  }
#pragma unroll
  for (int dvt = 0; dvt < 4; ++dvt)
    out[((size_t)b * kS + i0 + en) * kC + dvt * 16 + em] = Of[dvt];
}

// ---------------------------------------------------------------------------
extern "C" void kernel_launch(void* const* d_in, const int* in_sizes, int n_in,
                              void* d_out, int out_size, void* d_ws, size_t ws_size,
                              hipStream_t stream) {
  const float* q      = (const float*)d_in[0];
  const float* k      = (const float*)d_in[1];
  const float* v      = (const float*)d_in[2];
  const float* conv_w = (const float*)d_in[3];
  const float* nq_w   = (const float*)d_in[4];
  const float* nk_w   = (const float*)d_in[5];
  const float* wq     = (const float*)d_in[6];
  const float* bq     = (const float*)d_in[7];
  const float* wk     = (const float*)d_in[8];
  const float* bk     = (const float*)d_in[9];
  float* out = (float*)d_out;

  const size_t N = (size_t)kB * kS * kC;   // 1,179,648
  short* qt  = (short*)d_ws;     // bf16 [b][s][c]
  short* kt  = qt + N;
  short* vt  = kt + N;           // bf16 [b][c][s]
  short* qp  = vt + N;           // bf16 [b][s][64]
  short* kp  = qp + N;
  short* wqb = kp + N;           // bf16 [64][64]
  short* wkb = wqb + 4096;
  short* wt2 = wkb + 4096;       // bf16 [9][64][64]

  fused_prep<<<1904, 256, 0, stream>>>(q, k, v, wq, wk, conv_w,
                                       qt, kt, vt, wqb, wkb, wt2);
  fused_qk_gemm<<<576, 256, 0, stream>>>(qt, kt, wt2, wqb, wkb,
                                         nq_w, nk_w, bq, bk, qp, kp);
  attn_mfma<<<dim3(kS / 16, kB), 256, 0, stream>>>(qp, kp, vt, out);
}

// Round 8
// 250.678 us; speedup vs baseline: 1.0798x; 1.0798x over previous
//
#include <hip/hip_runtime.h>
#include <hip/hip_bf16.h>

namespace {
constexpr int kB = 8;
constexpr int kC = 64;
constexpr int kH = 48;
constexpr int kW = 48;
constexpr int kS = kH * kW;          // 2304
constexpr float kEps = 1.1920929e-07f;
}

typedef __attribute__((ext_vector_type(8))) short short8;   // 8 bf16 (4 VGPR)
typedef __attribute__((ext_vector_type(4))) short short4_t; // 4 bf16 (2 VGPR)
typedef __attribute__((ext_vector_type(4))) float f32x4;

// fp32 -> bf16 (round-nearest-even), bit-level
__device__ __forceinline__ short f2bf(float x) {
  unsigned u = __float_as_uint(x);
  u += 0x7fffu + ((u >> 16) & 1u);
  return (short)(u >> 16);
}
__device__ __forceinline__ float bf2f(short s) {
  return __uint_as_float(((unsigned)(unsigned short)s) << 16);
}

// ---------------------------------------------------------------------------
// F1: fused prep (unchanged from round 7).
// ---------------------------------------------------------------------------
__global__ __launch_bounds__(256) void fused_prep(
    const float* __restrict__ q, const float* __restrict__ k,
    const float* __restrict__ v, const float* __restrict__ wq,
    const float* __restrict__ wk, const float* __restrict__ conv_w,
    short* __restrict__ qt, short* __restrict__ kt, short* __restrict__ vt,
    short* __restrict__ wqb, short* __restrict__ wkb, short* __restrict__ wt2) {
  const int blk = blockIdx.x;
  if (blk < 576) {
    __shared__ float tile[64][65];
    const int zz = blk / 36;         // b*2 + which
    const int bx = blk % 36;
    const int b = zz >> 1;
    const float* src = (zz & 1) ? k : q;
    short* dst = (zz & 1) ? kt : qt;
    const int s0 = bx * 64;
    const int tx = threadIdx.x & 63;
    const int ty = threadIdx.x >> 6;
#pragma unroll
    for (int r = 0; r < 16; ++r) {
      int c = r * 4 + ty;
      tile[c][tx] = src[((size_t)b * kC + c) * kS + s0 + tx];
    }
    __syncthreads();
#pragma unroll
    for (int r = 0; r < 16; ++r) {
      int s = r * 4 + ty;
      dst[((size_t)b * kS + s0 + s) * kC + tx] = f2bf(tile[tx][s]);
    }
  } else if (blk < 1728) {
    int idx = ((blk - 576) * 256 + threadIdx.x) * 4;
    float4 x = *reinterpret_cast<const float4*>(v + idx);
    int2 o;
    o.x = ((int)(unsigned short)f2bf(x.y) << 16) | (unsigned short)f2bf(x.x);
    o.y = ((int)(unsigned short)f2bf(x.w) << 16) | (unsigned short)f2bf(x.z);
    *reinterpret_cast<int2*>(vt + idx) = o;
  } else {
    int idx = (blk - 1728) * 256 + threadIdx.x;
    if (idx < 4096) {
      wqb[idx] = f2bf(wq[idx]);
    } else if (idx < 8192) {
      wkb[idx - 4096] = f2bf(wk[idx - 4096]);
    } else {
      int i = idx - 8192;
      int ci = i & 63, co = (i >> 6) & 63, tap = i >> 12;
      wt2[i] = f2bf(conv_w[co * 576 + ci * 9 + tap]);
    }
  }
}

// ---------------------------------------------------------------------------
// F2: fused q/k projection GEMMs. Only change vs round 7: the q-path scale
// folds log2(e) so attention can use exp2 (bare v_exp_f32):
// 0.25 * 1.4426950408889634 = 0.36067376022224085
// ---------------------------------------------------------------------------
__global__ __launch_bounds__(256) void fused_qk_gemm(
    const short* __restrict__ qt, const short* __restrict__ kt,
    const short* __restrict__ wt2, const short* __restrict__ wqb,
    const short* __restrict__ wkb,
    const float* __restrict__ nq_w, const float* __restrict__ nk_w,
    const float* __restrict__ bq, const float* __restrict__ bk,
    short* __restrict__ qp, short* __restrict__ kp) {
  __shared__ __align__(16) short ln[4][16][80];
  const int blk = blockIdx.x;
  const int t = threadIdx.x;
  const int ws = t >> 6;
  const int L = t & 63;
  const int quad = L >> 4;
  const int l16 = L & 15;
  const short8 zero8 = {0, 0, 0, 0, 0, 0, 0, 0};

  if (blk < 288) {
    // ---- q path ----
    const int b = blk / 36;
    const int sBase = (blk % 36) * 64 + ws * 16;
    const int s = sBase + l16;
    const int h = s / kW, w = s % kW;

    f32x4 acc[4] = {{0.f, 0.f, 0.f, 0.f}, {0.f, 0.f, 0.f, 0.f},
                    {0.f, 0.f, 0.f, 0.f}, {0.f, 0.f, 0.f, 0.f}};
#pragma unroll
    for (int tap = 0; tap < 9; ++tap) {
      const int dh = tap / 3 - 1, dw = tap % 3 - 1;
      const bool valid = (unsigned)(h + dh) < (unsigned)kH &&
                         (unsigned)(w + dw) < (unsigned)kW;
      const int srow = valid ? (s + dh * kW + dw) : s;
      const short8* ap = reinterpret_cast<const short8*>(
          qt + ((size_t)b * kS + srow) * kC);
#pragma unroll
      for (int kh = 0; kh < 2; ++kh) {
        short8 af = ap[kh * 4 + quad];
        af = valid ? af : zero8;
        const short* wb = wt2 + tap * 4096 + l16 * kC + kh * 32 + quad * 8;
#pragma unroll
        for (int nt = 0; nt < 4; ++nt) {
          short8 bf = *reinterpret_cast<const short8*>(wb + nt * 16 * kC);
          acc[nt] = __builtin_amdgcn_mfma_f32_16x16x32_bf16(af, bf, acc[nt], 0, 0, 0);
        }
      }
    }
    float rstd[4];
#pragma unroll
    for (int reg = 0; reg < 4; ++reg) {
      float pr = acc[0][reg] * acc[0][reg] + acc[1][reg] * acc[1][reg]
               + acc[2][reg] * acc[2][reg] + acc[3][reg] * acc[3][reg];
      pr += __shfl_xor(pr, 1, 64);
      pr += __shfl_xor(pr, 2, 64);
      pr += __shfl_xor(pr, 4, 64);
      pr += __shfl_xor(pr, 8, 64);
      rstd[reg] = rsqrtf(pr * (1.0f / kC) + kEps);
    }
#pragma unroll
    for (int nt = 0; nt < 4; ++nt) {
      float g = nq_w[nt * 16 + l16];
#pragma unroll
      for (int reg = 0; reg < 4; ++reg) {
        ln[ws][quad * 4 + reg][nt * 16 + l16] = f2bf(acc[nt][reg] * rstd[reg] * g);
      }
    }
    __syncthreads();
    f32x4 acc2[4] = {{0.f, 0.f, 0.f, 0.f}, {0.f, 0.f, 0.f, 0.f},
                     {0.f, 0.f, 0.f, 0.f}, {0.f, 0.f, 0.f, 0.f}};
#pragma unroll
    for (int kh = 0; kh < 2; ++kh) {
      short8 af = *reinterpret_cast<const short8*>(&ln[ws][l16][kh * 32 + quad * 8]);
#pragma unroll
      for (int nt = 0; nt < 4; ++nt) {
        short8 bf = *reinterpret_cast<const short8*>(
            wqb + (nt * 16 + l16) * kC + kh * 32 + quad * 8);
        acc2[nt] = __builtin_amdgcn_mfma_f32_16x16x32_bf16(af, bf, acc2[nt], 0, 0, 0);
      }
    }
#pragma unroll
    for (int nt = 0; nt < 4; ++nt) {
      const int e = nt * 16 + l16;
      float bias = bq[e];
#pragma unroll
      for (int reg = 0; reg < 4; ++reg) {
        qp[((size_t)b * kS + sBase + quad * 4 + reg) * kC + e] =
            f2bf((acc2[nt][reg] + bias) * 0.36067376022224085f);
      }
    }
  } else {
    // ---- k path ----
    const int idx = blk - 288;
    const int b = idx / 36;
    const int sBase = (idx % 36) * 64 + ws * 16;
    const int s = sBase + l16;

    const short8* ap = reinterpret_cast<const short8*>(
        kt + ((size_t)b * kS + s) * kC);
    short8 af0 = ap[quad];
    short8 af1 = ap[4 + quad];

    float xs[16];
#pragma unroll
    for (int j = 0; j < 8; ++j) { xs[j] = bf2f(af0[j]); xs[8 + j] = bf2f(af1[j]); }
    float sum = 0.f;
#pragma unroll
    for (int j = 0; j < 16; ++j) sum = fmaf(xs[j], xs[j], sum);
    sum += __shfl_xor(sum, 16, 64);
    sum += __shfl_xor(sum, 32, 64);
    float rstd = rsqrtf(sum * (1.0f / kC) + kEps);

    const float* n0 = nk_w + quad * 8;
#pragma unroll
    for (int j = 0; j < 8; ++j) {
      af0[j] = f2bf(xs[j] * rstd * n0[j]);
      af1[j] = f2bf(xs[8 + j] * rstd * n0[32 + j]);
    }

    f32x4 acc[4] = {{0.f, 0.f, 0.f, 0.f}, {0.f, 0.f, 0.f, 0.f},
                    {0.f, 0.f, 0.f, 0.f}, {0.f, 0.f, 0.f, 0.f}};
#pragma unroll
    for (int nt = 0; nt < 4; ++nt) {
      short8 bf0 = *reinterpret_cast<const short8*>(
          wkb + (nt * 16 + l16) * kC + quad * 8);
      short8 bf1 = *reinterpret_cast<const short8*>(
          wkb + (nt * 16 + l16) * kC + 32 + quad * 8);
      acc[nt] = __builtin_amdgcn_mfma_f32_16x16x32_bf16(af0, bf0, acc[nt], 0, 0, 0);
      acc[nt] = __builtin_amdgcn_mfma_f32_16x16x32_bf16(af1, bf1, acc[nt], 0, 0, 0);
    }
#pragma unroll
    for (int nt = 0; nt < 4; ++nt) {
      const int e = nt * 16 + l16;
      float bias = bk[e];
#pragma unroll
      for (int reg = 0; reg < 4; ++reg) {
        kp[((size_t)b * kS + sBase + quad * 4 + reg) * kC + e] =
            f2bf(acc[nt][reg] + bias);
      }
    }
  }
}

// ---------------------------------------------------------------------------
// K3: LDS-staged flash attention, single pass, per-head unnormalized U.
// grid 576 (1D): b = blk&7 (XCD-local K/V), i0 = (blk>>3)*32.
// 4 waves: isub = ws&1 (which 16 i's), jhalf = ws>>1 (which 32 j's of tile).
// Per 64-j tile: K-tile [j][c] (pitch 72) and V^T-tile [c][j] (pitch 76)
// staged in LDS (double-buffered, coalesced 128B global reads, b128 writes).
// Inner: S^T = mfma16(A=K,B=Q) -> exp2 -> P^T (B-layout in regs) ->
// U[h][d] += mfma16(A=V^T, B=P^T). One barrier per tile.
// Epilogue: 3 barriers, register head-combine, dwordx4 stores.
// ---------------------------------------------------------------------------
__global__ __launch_bounds__(256) void attn_flash(
    const short* __restrict__ qp, const short* __restrict__ kp,
    const short* __restrict__ vt, float* __restrict__ out) {
  __shared__ __align__(16) char pool[2 * 64 * 72 * 2 + 2 * 64 * 76 * 2]; // 37888
  __shared__ float pl[4][16][4];   // [ws][i16][h]
  __shared__ float Li[32][4];      // 0.25 / l

  short (*Kt)[64][72] = reinterpret_cast<short (*)[64][72]>(pool);
  short (*Vt)[64][76] = reinterpret_cast<short (*)[64][76]>(pool + 2 * 64 * 72 * 2);

  const int blk = blockIdx.x;
  const int b = blk & 7;
  const int i0 = (blk >> 3) * 32;
  const int t = threadIdx.x;
  const int ws = t >> 6;
  const int L = t & 63;
  const int quad = L >> 4;
  const int l16 = L & 15;
  const int isub = ws & 1;
  const int jhalf = ws >> 1;

  const f32x4 zc = {0.f, 0.f, 0.f, 0.f};

  // Q fragments (B operand): row i = i0 + isub*16 + l16, head h dims h*16+quad*4
  const short* qrow = qp + ((size_t)b * kS + i0 + isub * 16 + l16) * kC + quad * 4;
  short4_t qh[4];
#pragma unroll
  for (int h = 0; h < 4; ++h)
    qh[h] = *reinterpret_cast<const short4_t*>(qrow + h * 16);

  // staging source geometry: octet covers one 128B row
  const int r8 = t >> 3;    // 0..31
  const int seg = t & 7;
  const short* kg = kp + (size_t)b * kS * kC;
  const short* vg = vt + (size_t)b * kC * kS;

  int4 kreg[2], vreg[2];
  // prologue: stage tile 0
#pragma unroll
  for (int pass = 0; pass < 2; ++pass) {
    kreg[pass] = *reinterpret_cast<const int4*>(
        kg + (size_t)(pass * 32 + r8) * kC + seg * 8);
    vreg[pass] = *reinterpret_cast<const int4*>(
        vg + (size_t)(pass * 32 + r8) * kS + seg * 8);
  }
#pragma unroll
  for (int pass = 0; pass < 2; ++pass) {
    *reinterpret_cast<int4*>(&Kt[0][pass * 32 + r8][seg * 8]) = kreg[pass];
    *reinterpret_cast<int4*>(&Vt[0][pass * 32 + r8][seg * 8]) = vreg[pass];
  }
  __syncthreads();

  f32x4 U[4][4];   // [h][dtile] O^T fragments
#pragma unroll
  for (int h = 0; h < 4; ++h)
#pragma unroll
    for (int d = 0; d < 4; ++d) U[h][d] = zc;
  float lh[4] = {0.f, 0.f, 0.f, 0.f};

  for (int jt = 0; jt < kS / 64; ++jt) {
    const int buf = jt & 1;
    const bool more = (jt + 1) < kS / 64;
    if (more) {
      const int jn = (jt + 1) * 64;
#pragma unroll
      for (int pass = 0; pass < 2; ++pass) {
        kreg[pass] = *reinterpret_cast<const int4*>(
            kg + (size_t)(jn + pass * 32 + r8) * kC + seg * 8);
        vreg[pass] = *reinterpret_cast<const int4*>(
            vg + (size_t)(pass * 32 + r8) * kS + jn + seg * 8);
      }
    }

#pragma unroll
    for (int cc = 0; cc < 2; ++cc) {
      const int chunk = jhalf * 2 + cc;
      short4_t kf[4], vf[4];
#pragma unroll
      for (int h = 0; h < 4; ++h)
        kf[h] = *reinterpret_cast<const short4_t*>(
            &Kt[buf][chunk * 16 + l16][h * 16 + quad * 4]);
#pragma unroll
      for (int d = 0; d < 4; ++d)
        vf[d] = *reinterpret_cast<const short4_t*>(
            &Vt[buf][d * 16 + l16][chunk * 16 + quad * 4]);

      short4_t p[4];
#pragma unroll
      for (int h = 0; h < 4; ++h) {
        f32x4 s = __builtin_amdgcn_mfma_f32_16x16x16bf16_1k(kf[h], qh[h], zc, 0, 0, 0);
        float e0 = exp2f(s[0]), e1 = exp2f(s[1]);
        float e2 = exp2f(s[2]), e3 = exp2f(s[3]);
        lh[h] += (e0 + e1) + (e2 + e3);
        union { __hip_bfloat162 h2[2]; short4_t s4; } cv;
        cv.h2[0] = __float22bfloat162_rn(make_float2(e0, e1));
        cv.h2[1] = __float22bfloat162_rn(make_float2(e2, e3));
        p[h] = cv.s4;
      }
#pragma unroll
      for (int h = 0; h < 4; ++h)
#pragma unroll
        for (int d = 0; d < 4; ++d)
          U[h][d] = __builtin_amdgcn_mfma_f32_16x16x16bf16_1k(vf[d], p[h], U[h][d], 0, 0, 0);
    }

    if (more) {
      const int nb = buf ^ 1;
#pragma unroll
      for (int pass = 0; pass < 2; ++pass) {
        *reinterpret_cast<int4*>(&Kt[nb][pass * 32 + r8][seg * 8]) = kreg[pass];
        *reinterpret_cast<int4*>(&Vt[nb][pass * 32 + r8][seg * 8]) = vreg[pass];
      }
    }
    __syncthreads();
  }

  // ---- epilogue ----
#pragma unroll
  for (int h = 0; h < 4; ++h) {
    lh[h] += __shfl_xor(lh[h], 16, 64);
    lh[h] += __shfl_xor(lh[h], 32, 64);
  }
  if (quad == 0) {
#pragma unroll
    for (int h = 0; h < 4; ++h) pl[ws][l16][h] = lh[h];
  }
  __syncthreads();
  if (t < 128) {
    const int i = t >> 2, h = t & 3;   // i 0..31
    Li[i][h] = 0.25f / (pl[i >> 4][i & 15][h] + pl[(i >> 4) + 2][i & 15][h]);
  }
  // U exchange: jhalf==1 waves dump their U into pool (aliases K/V tiles)
  float* ub = reinterpret_cast<float*>(pool);
  if (jhalf == 1) {
#pragma unroll
    for (int h = 0; h < 4; ++h)
#pragma unroll
      for (int d = 0; d < 4; ++d)
        *reinterpret_cast<f32x4*>(&ub[((isub * 16 + h * 4 + d) * 64 + L) * 4]) = U[h][d];
  }
  __syncthreads();
  if (jhalf == 0) {
    float li[4];
#pragma unroll
    for (int h = 0; h < 4; ++h) li[h] = Li[isub * 16 + l16][h];
#pragma unroll
    for (int d = 0; d < 4; ++d) {
      f32x4 o = zc;
#pragma unroll
      for (int h = 0; h < 4; ++h) {
        f32x4 up = *reinterpret_cast<const f32x4*>(
            &ub[((isub * 16 + h * 4 + d) * 64 + L) * 4]);
#pragma unroll
        for (int r = 0; r < 4; ++r) o[r] += (U[h][d][r] + up[r]) * li[h];
      }
      *reinterpret_cast<float4*>(
          out + ((size_t)b * kS + i0 + isub * 16 + l16) * kC + d * 16 + quad * 4) =
          make_float4(o[0], o[1], o[2], o[3]);
    }
  }
}

// ---------------------------------------------------------------------------
extern "C" void kernel_launch(void* const* d_in, const int* in_sizes, int n_in,
                              void* d_out, int out_size, void* d_ws, size_t ws_size,
                              hipStream_t stream) {
  const float* q      = (const float*)d_in[0];
  const float* k      = (const float*)d_in[1];
  const float* v      = (const float*)d_in[2];
  const float* conv_w = (const float*)d_in[3];
  const float* nq_w   = (const float*)d_in[4];
  const float* nk_w   = (const float*)d_in[5];
  const float* wq     = (const float*)d_in[6];
  const float* bq     = (const float*)d_in[7];
  const float* wk     = (const float*)d_in[8];
  const float* bk     = (const float*)d_in[9];
  float* out = (float*)d_out;

  const size_t N = (size_t)kB * kS * kC;   // 1,179,648
  short* qt  = (short*)d_ws;     // bf16 [b][s][c]
  short* kt  = qt + N;
  short* vt  = kt + N;           // bf16 [b][c][s]
  short* qp  = vt + N;           // bf16 [b][s][64]
  short* kp  = qp + N;
  short* wqb = kp + N;           // bf16 [64][64]
  short* wkb = wqb + 4096;
  short* wt2 = wkb + 4096;       // bf16 [9][64][64]

  fused_prep<<<1904, 256, 0, stream>>>(q, k, v, wq, wk, conv_w,
                                       qt, kt, vt, wqb, wkb, wt2);
  fused_qk_gemm<<<576, 256, 0, stream>>>(qt, kt, wt2, wqb, wkb,
                                         nq_w, nk_w, bq, bk, qp, kp);
  attn_flash<<<576, 256, 0, stream>>>(qp, kp, vt, out);
}

// Round 9
// 188.286 us; speedup vs baseline: 1.4376x; 1.3314x over previous
//
#include <hip/hip_runtime.h>
#include <hip/hip_bf16.h>

namespace {
constexpr int kB = 8;
constexpr int kC = 64;
constexpr int kH = 48;
constexpr int kW = 48;
constexpr int kS = kH * kW;          // 2304
constexpr float kEps = 1.1920929e-07f;
}

typedef __attribute__((ext_vector_type(8))) short short8;   // 8 bf16 (4 VGPR)
typedef __attribute__((ext_vector_type(4))) short short4_t; // 4 bf16 (2 VGPR)
typedef __attribute__((ext_vector_type(4))) float f32x4;

// fp32 -> bf16 (round-nearest-even), bit-level
__device__ __forceinline__ short f2bf(float x) {
  unsigned u = __float_as_uint(x);
  u += 0x7fffu + ((u >> 16) & 1u);
  return (short)(u >> 16);
}
__device__ __forceinline__ float bf2f(short s) {
  return __uint_as_float(((unsigned)(unsigned short)s) << 16);
}

// ---------------------------------------------------------------------------
// F1: fused prep (unchanged).
// ---------------------------------------------------------------------------
__global__ __launch_bounds__(256) void fused_prep(
    const float* __restrict__ q, const float* __restrict__ k,
    const float* __restrict__ v, const float* __restrict__ wq,
    const float* __restrict__ wk, const float* __restrict__ conv_w,
    short* __restrict__ qt, short* __restrict__ kt, short* __restrict__ vt,
    short* __restrict__ wqb, short* __restrict__ wkb, short* __restrict__ wt2) {
  const int blk = blockIdx.x;
  if (blk < 576) {
    __shared__ float tile[64][65];
    const int zz = blk / 36;         // b*2 + which
    const int bx = blk % 36;
    const int b = zz >> 1;
    const float* src = (zz & 1) ? k : q;
    short* dst = (zz & 1) ? kt : qt;
    const int s0 = bx * 64;
    const int tx = threadIdx.x & 63;
    const int ty = threadIdx.x >> 6;
#pragma unroll
    for (int r = 0; r < 16; ++r) {
      int c = r * 4 + ty;
      tile[c][tx] = src[((size_t)b * kC + c) * kS + s0 + tx];
    }
    __syncthreads();
#pragma unroll
    for (int r = 0; r < 16; ++r) {
      int s = r * 4 + ty;
      dst[((size_t)b * kS + s0 + s) * kC + tx] = f2bf(tile[tx][s]);
    }
  } else if (blk < 1728) {
    int idx = ((blk - 576) * 256 + threadIdx.x) * 4;
    float4 x = *reinterpret_cast<const float4*>(v + idx);
    int2 o;
    o.x = ((int)(unsigned short)f2bf(x.y) << 16) | (unsigned short)f2bf(x.x);
    o.y = ((int)(unsigned short)f2bf(x.w) << 16) | (unsigned short)f2bf(x.z);
    *reinterpret_cast<int2*>(vt + idx) = o;
  } else {
    int idx = (blk - 1728) * 256 + threadIdx.x;
    if (idx < 4096) {
      wqb[idx] = f2bf(wq[idx]);
    } else if (idx < 8192) {
      wkb[idx - 4096] = f2bf(wk[idx - 4096]);
    } else {
      int i = idx - 8192;
      int ci = i & 63, co = (i >> 6) & 63, tap = i >> 12;
      wt2[i] = f2bf(conv_w[co * 576 + ci * 9 + tap]);
    }
  }
}

// ---------------------------------------------------------------------------
// F2: fused q/k projection GEMMs.
// q path now stages the 164-row qt halo tile in LDS (coalesced) to kill the
// per-frag 16-line global scatter. q scale folds 0.25*log2(e).
// ---------------------------------------------------------------------------
__global__ __launch_bounds__(256) void fused_qk_gemm(
    const short* __restrict__ qt, const short* __restrict__ kt,
    const short* __restrict__ wt2, const short* __restrict__ wqb,
    const short* __restrict__ wkb,
    const float* __restrict__ nq_w, const float* __restrict__ nk_w,
    const float* __restrict__ bq, const float* __restrict__ bk,
    short* __restrict__ qp, short* __restrict__ kp) {
  __shared__ __align__(16) short Qs[164][72];   // halo-staged qt rows
  __shared__ __align__(16) short ln[4][16][80];
  const int blk = blockIdx.x;
  const int t = threadIdx.x;
  const int ws = t >> 6;
  const int L = t & 63;
  const int quad = L >> 4;
  const int l16 = L & 15;
  const short8 zero8 = {0, 0, 0, 0, 0, 0, 0, 0};

  if (blk < 288) {
    // ---- q path ----
    const int b = blk / 36;
    const int S0 = (blk % 36) * 64;
    const int sBase = S0 + ws * 16;
    const int s = sBase + l16;
    const int h = s / kW, w = s % kW;

    // stage rows [S0-49, S0+115) clamped; 164 rows x 8 int4
    const short* qtb = qt + (size_t)b * kS * kC;
#pragma unroll
    for (int it = 0; it < 6; ++it) {
      int idx = it * 256 + t;
      if (idx < 164 * 8) {
        int r = idx >> 3, sg = idx & 7;
        int srow = S0 - 49 + r;
        srow = srow < 0 ? 0 : (srow >= kS ? kS - 1 : srow);
        *reinterpret_cast<int4*>(&Qs[r][sg * 8]) =
            *reinterpret_cast<const int4*>(qtb + (size_t)srow * kC + sg * 8);
      }
    }
    __syncthreads();

    const int baseLocal = ws * 16 + l16 + 49;
    f32x4 acc[4] = {{0.f, 0.f, 0.f, 0.f}, {0.f, 0.f, 0.f, 0.f},
                    {0.f, 0.f, 0.f, 0.f}, {0.f, 0.f, 0.f, 0.f}};
#pragma unroll
    for (int tap = 0; tap < 9; ++tap) {
      const int dh = tap / 3 - 1, dw = tap % 3 - 1;
      const bool valid = (unsigned)(h + dh) < (unsigned)kH &&
                         (unsigned)(w + dw) < (unsigned)kW;
      const int local = baseLocal + dh * kW + dw;
#pragma unroll
      for (int kh = 0; kh < 2; ++kh) {
        short8 af = *reinterpret_cast<const short8*>(&Qs[local][kh * 32 + quad * 8]);
        af = valid ? af : zero8;
        const short* wb = wt2 + tap * 4096 + l16 * kC + kh * 32 + quad * 8;
#pragma unroll
        for (int nt = 0; nt < 4; ++nt) {
          short8 bf = *reinterpret_cast<const short8*>(wb + nt * 16 * kC);
          acc[nt] = __builtin_amdgcn_mfma_f32_16x16x32_bf16(af, bf, acc[nt], 0, 0, 0);
        }
      }
    }
    float rstd[4];
#pragma unroll
    for (int reg = 0; reg < 4; ++reg) {
      float pr = acc[0][reg] * acc[0][reg] + acc[1][reg] * acc[1][reg]
               + acc[2][reg] * acc[2][reg] + acc[3][reg] * acc[3][reg];
      pr += __shfl_xor(pr, 1, 64);
      pr += __shfl_xor(pr, 2, 64);
      pr += __shfl_xor(pr, 4, 64);
      pr += __shfl_xor(pr, 8, 64);
      rstd[reg] = rsqrtf(pr * (1.0f / kC) + kEps);
    }
#pragma unroll
    for (int nt = 0; nt < 4; ++nt) {
      float g = nq_w[nt * 16 + l16];
#pragma unroll
      for (int reg = 0; reg < 4; ++reg) {
        ln[ws][quad * 4 + reg][nt * 16 + l16] = f2bf(acc[nt][reg] * rstd[reg] * g);
      }
    }
    __syncthreads();
    f32x4 acc2[4] = {{0.f, 0.f, 0.f, 0.f}, {0.f, 0.f, 0.f, 0.f},
                     {0.f, 0.f, 0.f, 0.f}, {0.f, 0.f, 0.f, 0.f}};
#pragma unroll
    for (int kh = 0; kh < 2; ++kh) {
      short8 af = *reinterpret_cast<const short8*>(&ln[ws][l16][kh * 32 + quad * 8]);
#pragma unroll
      for (int nt = 0; nt < 4; ++nt) {
        short8 bf = *reinterpret_cast<const short8*>(
            wqb + (nt * 16 + l16) * kC + kh * 32 + quad * 8);
        acc2[nt] = __builtin_amdgcn_mfma_f32_16x16x32_bf16(af, bf, acc2[nt], 0, 0, 0);
      }
    }
#pragma unroll
    for (int nt = 0; nt < 4; ++nt) {
      const int e = nt * 16 + l16;
      float bias = bq[e];
#pragma unroll
      for (int reg = 0; reg < 4; ++reg) {
        qp[((size_t)b * kS + sBase + quad * 4 + reg) * kC + e] =
            f2bf((acc2[nt][reg] + bias) * 0.36067376022224085f);
      }
    }
  } else {
    // ---- k path (unchanged) ----
    const int idx = blk - 288;
    const int b = idx / 36;
    const int sBase = (idx % 36) * 64 + ws * 16;
    const int s = sBase + l16;

    const short8* ap = reinterpret_cast<const short8*>(
        kt + ((size_t)b * kS + s) * kC);
    short8 af0 = ap[quad];
    short8 af1 = ap[4 + quad];

    float xs[16];
#pragma unroll
    for (int j = 0; j < 8; ++j) { xs[j] = bf2f(af0[j]); xs[8 + j] = bf2f(af1[j]); }
    float sum = 0.f;
#pragma unroll
    for (int j = 0; j < 16; ++j) sum = fmaf(xs[j], xs[j], sum);
    sum += __shfl_xor(sum, 16, 64);
    sum += __shfl_xor(sum, 32, 64);
    float rstd = rsqrtf(sum * (1.0f / kC) + kEps);

    const float* n0 = nk_w + quad * 8;
#pragma unroll
    for (int j = 0; j < 8; ++j) {
      af0[j] = f2bf(xs[j] * rstd * n0[j]);
      af1[j] = f2bf(xs[8 + j] * rstd * n0[32 + j]);
    }

    f32x4 acc[4] = {{0.f, 0.f, 0.f, 0.f}, {0.f, 0.f, 0.f, 0.f},
                    {0.f, 0.f, 0.f, 0.f}, {0.f, 0.f, 0.f, 0.f}};
#pragma unroll
    for (int nt = 0; nt < 4; ++nt) {
      short8 bf0 = *reinterpret_cast<const short8*>(
          wkb + (nt * 16 + l16) * kC + quad * 8);
      short8 bf1 = *reinterpret_cast<const short8*>(
          wkb + (nt * 16 + l16) * kC + 32 + quad * 8);
      acc[nt] = __builtin_amdgcn_mfma_f32_16x16x32_bf16(af0, bf0, acc[nt], 0, 0, 0);
      acc[nt] = __builtin_amdgcn_mfma_f32_16x16x32_bf16(af1, bf1, acc[nt], 0, 0, 0);
    }
#pragma unroll
    for (int nt = 0; nt < 4; ++nt) {
      const int e = nt * 16 + l16;
      float bias = bk[e];
#pragma unroll
      for (int reg = 0; reg < 4; ++reg) {
        kp[((size_t)b * kS + sBase + quad * 4 + reg) * kC + e] =
            f2bf(acc[nt][reg] + bias);
      }
    }
  }
}

// ---------------------------------------------------------------------------
// K3: LDS-staged flash attention, occupancy-first.
// grid 1152 (1D): b = blk&7, i0 = (blk>>3)*16. 256 thr, 4 waves; wave ws owns
// the 16-j quarter of each staged 64-j tile. __launch_bounds__(256,4) keeps
// VGPR<=128 so 4 blocks/CU co-reside (LDS 4x38.3 KB <= 160) — barrier stalls
// overlap across blocks. Per tile: 4 QK mfma16 + 16 exp2 + 16 PV mfma16,
// double-buffered staging, one barrier. Epilogue: conflict-free slab reduce
// over the 4 j-quarter waves.
// ---------------------------------------------------------------------------
__global__ __launch_bounds__(256, 4) void attn_flash(
    const short* __restrict__ qp, const short* __restrict__ kp,
    const short* __restrict__ vt, float* __restrict__ out) {
  __shared__ __align__(16) char pool[2 * 64 * 72 * 2 + 2 * 64 * 76 * 2]; // 37888
  __shared__ float pl[4][16][4];   // [ws][i][h]
  __shared__ float Li[16][4];      // 0.25 / l

  short (*Kt)[64][72] = reinterpret_cast<short (*)[64][72]>(pool);
  short (*Vt)[64][76] = reinterpret_cast<short (*)[64][76]>(pool + 2 * 64 * 72 * 2);
  float* slabF = reinterpret_cast<float*>(pool);   // epilogue alias

  const int blk = blockIdx.x;
  const int b = blk & 7;
  const int i0 = (blk >> 3) * 16;
  const int t = threadIdx.x;
  const int ws = t >> 6;           // j-quarter
  const int L = t & 63;
  const int quad = L >> 4;
  const int l16 = L & 15;

  const f32x4 zc = {0.f, 0.f, 0.f, 0.f};

  // Q fragments (B operand): row i = i0+l16, head h dims h*16+quad*4
  const short* qrow = qp + ((size_t)b * kS + i0 + l16) * kC + quad * 4;
  short4_t qh[4];
#pragma unroll
  for (int h = 0; h < 4; ++h)
    qh[h] = *reinterpret_cast<const short4_t*>(qrow + h * 16);

  // staging: octet covers one 128B row; 2 passes of 32 rows
  const int r8i = t >> 3;   // 0..31
  const int seg = t & 7;
  const short* kg = kp + (size_t)b * kS * kC;
  const short* vg = vt + (size_t)b * kC * kS;

  int4 kreg[2], vreg[2];
#pragma unroll
  for (int pass = 0; pass < 2; ++pass) {
    kreg[pass] = *reinterpret_cast<const int4*>(
        kg + (size_t)(pass * 32 + r8i) * kC + seg * 8);
    vreg[pass] = *reinterpret_cast<const int4*>(
        vg + (size_t)(pass * 32 + r8i) * kS + seg * 8);
  }
#pragma unroll
  for (int pass = 0; pass < 2; ++pass) {
    *reinterpret_cast<int4*>(&Kt[0][pass * 32 + r8i][seg * 8]) = kreg[pass];
    *reinterpret_cast<int4*>(&Vt[0][pass * 32 + r8i][seg * 8]) = vreg[pass];
  }
  __syncthreads();

  f32x4 U[4][4];   // [h][dtile] O^T fragments (this wave's j-stripe partial)
#pragma unroll
  for (int h = 0; h < 4; ++h)
#pragma unroll
    for (int d = 0; d < 4; ++d) U[h][d] = zc;
  float lh[4] = {0.f, 0.f, 0.f, 0.f};

  for (int jt = 0; jt < kS / 64; ++jt) {
    const int buf = jt & 1;
    const bool more = (jt + 1) < kS / 64;
    if (more) {
      const int jn = (jt + 1) * 64;
#pragma unroll
      for (int pass = 0; pass < 2; ++pass) {
        kreg[pass] = *reinterpret_cast<const int4*>(
            kg + (size_t)(jn + pass * 32 + r8i) * kC + seg * 8);
        vreg[pass] = *reinterpret_cast<const int4*>(
            vg + (size_t)(pass * 32 + r8i) * kS + jn + seg * 8);
      }
    }

    // compute this wave's 16-j quarter
    short4_t kf[4], vf[4];
#pragma unroll
    for (int h = 0; h < 4; ++h)
      kf[h] = *reinterpret_cast<const short4_t*>(
          &Kt[buf][ws * 16 + l16][h * 16 + quad * 4]);
#pragma unroll
    for (int d = 0; d < 4; ++d)
      vf[d] = *reinterpret_cast<const short4_t*>(
          &Vt[buf][d * 16 + l16][ws * 16 + quad * 4]);

    short4_t p[4];
#pragma unroll
    for (int h = 0; h < 4; ++h) {
      f32x4 s = __builtin_amdgcn_mfma_f32_16x16x16bf16_1k(kf[h], qh[h], zc, 0, 0, 0);
      float e0 = exp2f(s[0]), e1 = exp2f(s[1]);
      float e2 = exp2f(s[2]), e3 = exp2f(s[3]);
      lh[h] += (e0 + e1) + (e2 + e3);
      union { __hip_bfloat162 h2[2]; short4_t s4; } cv;
      cv.h2[0] = __float22bfloat162_rn(make_float2(e0, e1));
      cv.h2[1] = __float22bfloat162_rn(make_float2(e2, e3));
      p[h] = cv.s4;
    }
#pragma unroll
    for (int h = 0; h < 4; ++h)
#pragma unroll
      for (int d = 0; d < 4; ++d)
        U[h][d] = __builtin_amdgcn_mfma_f32_16x16x16bf16_1k(vf[d], p[h], U[h][d], 0, 0, 0);

    if (more) {
      const int nb = buf ^ 1;
#pragma unroll
      for (int pass = 0; pass < 2; ++pass) {
        *reinterpret_cast<int4*>(&Kt[nb][pass * 32 + r8i][seg * 8]) = kreg[pass];
        *reinterpret_cast<int4*>(&Vt[nb][pass * 32 + r8i][seg * 8]) = vreg[pass];
      }
    }
    __syncthreads();
  }

  // ---- epilogue ----
#pragma unroll
  for (int h = 0; h < 4; ++h) {
    lh[h] += __shfl_xor(lh[h], 16, 64);
    lh[h] += __shfl_xor(lh[h], 32, 64);
  }
  if (quad == 0) {
#pragma unroll
    for (int h = 0; h < 4; ++h) pl[ws][l16][h] = lh[h];
  }
  __syncthreads();
  if (t < 64) {
    const int i = t >> 2, h = t & 3;
    Li[i][h] = 0.25f / (pl[0][i][h] + pl[1][i][h] + pl[2][i][h] + pl[3][i][h]);
  }
  __syncthreads();
  float c[4];
#pragma unroll
  for (int h = 0; h < 4; ++h) c[h] = Li[l16][h];

  // cross-wave U reduce, one d-tile per phase. slab[(sid*4+h)*4+reg][66] lane-major.
#pragma unroll
  for (int d = 0; d < 4; ++d) {
    if (ws != 0) {
      const int sid = ws - 1;
#pragma unroll
      for (int h = 0; h < 4; ++h)
#pragma unroll
        for (int reg = 0; reg < 4; ++reg)
          slabF[((sid * 4 + h) * 4 + reg) * 66 + L] = U[h][d][reg];
    }
    __syncthreads();
    if (ws == 0) {
      float of[4] = {0.f, 0.f, 0.f, 0.f};
#pragma unroll
      for (int h = 0; h < 4; ++h) {
#pragma unroll
        for (int reg = 0; reg < 4; ++reg) {
          float tot = U[h][d][reg]
                    + slabF[((0 * 4 + h) * 4 + reg) * 66 + L]
                    + slabF[((1 * 4 + h) * 4 + reg) * 66 + L]
                    + slabF[((2 * 4 + h) * 4 + reg) * 66 + L];
          of[reg] += tot * c[h];
        }
      }
      *reinterpret_cast<float4*>(
          out + ((size_t)b * kS + i0 + l16) * kC + d * 16 + quad * 4) =
          make_float4(of[0], of[1], of[2], of[3]);
    }
    __syncthreads();
  }
}

// ---------------------------------------------------------------------------
extern "C" void kernel_launch(void* const* d_in, const int* in_sizes, int n_in,
                              void* d_out, int out_size, void* d_ws, size_t ws_size,
                              hipStream_t stream) {
  const float* q      = (const float*)d_in[0];
  const float* k      = (const float*)d_in[1];
  const float* v      = (const float*)d_in[2];
  const float* conv_w = (const float*)d_in[3];
  const float* nq_w   = (const float*)d_in[4];
  const float* nk_w   = (const float*)d_in[5];
  const float* wq     = (const float*)d_in[6];
  const float* bq     = (const float*)d_in[7];
  const float* wk     = (const float*)d_in[8];
  const float* bk     = (const float*)d_in[9];
  float* out = (float*)d_out;

  const size_t N = (size_t)kB * kS * kC;   // 1,179,648
  short* qt  = (short*)d_ws;     // bf16 [b][s][c]
  short* kt  = qt + N;
  short* vt  = kt + N;           // bf16 [b][c][s]
  short* qp  = vt + N;           // bf16 [b][s][64]
  short* kp  = qp + N;
  short* wqb = kp + N;           // bf16 [64][64]
  short* wkb = wqb + 4096;
  short* wt2 = wkb + 4096;       // bf16 [9][64][64]

  fused_prep<<<1904, 256, 0, stream>>>(q, k, v, wq, wk, conv_w,
                                       qt, kt, vt, wqb, wkb, wt2);
  fused_qk_gemm<<<576, 256, 0, stream>>>(qt, kt, wt2, wqb, wkb,
                                         nq_w, nk_w, bq, bk, qp, kp);
  attn_flash<<<1152, 256, 0, stream>>>(qp, kp, vt, out);
}

// Round 10
// 176.562 us; speedup vs baseline: 1.5330x; 1.0664x over previous
//
#include <hip/hip_runtime.h>
#include <hip/hip_bf16.h>

namespace {
constexpr int kB = 8;
constexpr int kC = 64;
constexpr int kH = 48;
constexpr int kW = 48;
constexpr int kS = kH * kW;          // 2304
constexpr float kEps = 1.1920929e-07f;
}

typedef __attribute__((ext_vector_type(8))) short short8;   // 8 bf16 (4 VGPR)
typedef __attribute__((ext_vector_type(4))) short short4_t; // 4 bf16 (2 VGPR)
typedef __attribute__((ext_vector_type(4))) float f32x4;

// fp32 -> bf16 (round-nearest-even), bit-level
__device__ __forceinline__ short f2bf(float x) {
  unsigned u = __float_as_uint(x);
  u += 0x7fffu + ((u >> 16) & 1u);
  return (short)(u >> 16);
}
__device__ __forceinline__ float bf2f(short s) {
  return __uint_as_float(((unsigned)(unsigned short)s) << 16);
}

// ---------------------------------------------------------------------------
// F1: fused prep.
//  blocks [0,576):    transpose q,k [b][c][s] fp32 -> [b][s][c] bf16
//  blocks [576,1728): v fp32 -> bf16 cast
//  blocks [1728,1904): weights -> FRAG-MAJOR layouts:
//    wqb3/wkb3[(kh*4+nt)*512 + L*8 + j]   = w[e=nt*16+(L&15)][c=kh*32+(L>>4)*8+j]
//    wt3[((tap*2+kh)*4+nt)*512 + L*8 + j] = conv_w[co=nt*16+(L&15)][ci=...][tap]
//  so every MFMA B-frag load is one coalesced 1KB wave-load.
// ---------------------------------------------------------------------------
__global__ __launch_bounds__(256) void fused_prep(
    const float* __restrict__ q, const float* __restrict__ k,
    const float* __restrict__ v, const float* __restrict__ wq,
    const float* __restrict__ wk, const float* __restrict__ conv_w,
    short* __restrict__ qt, short* __restrict__ kt, short* __restrict__ vt,
    short* __restrict__ wqb3, short* __restrict__ wkb3, short* __restrict__ wt3) {
  const int blk = blockIdx.x;
  if (blk < 576) {
    __shared__ float tile[64][65];
    const int zz = blk / 36;         // b*2 + which
    const int bx = blk % 36;
    const int b = zz >> 1;
    const float* src = (zz & 1) ? k : q;
    short* dst = (zz & 1) ? kt : qt;
    const int s0 = bx * 64;
    const int tx = threadIdx.x & 63;
    const int ty = threadIdx.x >> 6;
#pragma unroll
    for (int r = 0; r < 16; ++r) {
      int c = r * 4 + ty;
      tile[c][tx] = src[((size_t)b * kC + c) * kS + s0 + tx];
    }
    __syncthreads();
#pragma unroll
    for (int r = 0; r < 16; ++r) {
      int s = r * 4 + ty;
      dst[((size_t)b * kS + s0 + s) * kC + tx] = f2bf(tile[tx][s]);
    }
  } else if (blk < 1728) {
    int idx = ((blk - 576) * 256 + threadIdx.x) * 4;
    float4 x = *reinterpret_cast<const float4*>(v + idx);
    int2 o;
    o.x = ((int)(unsigned short)f2bf(x.y) << 16) | (unsigned short)f2bf(x.x);
    o.y = ((int)(unsigned short)f2bf(x.w) << 16) | (unsigned short)f2bf(x.z);
    *reinterpret_cast<int2*>(vt + idx) = o;
  } else {
    int idx = (blk - 1728) * 256 + threadIdx.x;
    if (idx < 4096) {
      int j = idx & 7, Lw = (idx >> 3) & 63, slab = idx >> 9;
      int nt = slab & 3, kh = slab >> 2;
      int e = nt * 16 + (Lw & 15), c = kh * 32 + (Lw >> 4) * 8 + j;
      wqb3[idx] = f2bf(wq[e * 64 + c]);
    } else if (idx < 8192) {
      int i2 = idx - 4096;
      int j = i2 & 7, Lw = (i2 >> 3) & 63, slab = i2 >> 9;
      int nt = slab & 3, kh = slab >> 2;
      int e = nt * 16 + (Lw & 15), c = kh * 32 + (Lw >> 4) * 8 + j;
      wkb3[i2] = f2bf(wk[e * 64 + c]);
    } else {
      int i3 = idx - 8192;   // < 36864
      int j = i3 & 7, Lw = (i3 >> 3) & 63, slab = i3 >> 9;   // 0..71
      int nt = slab & 3, kh = (slab >> 2) & 1, tap = slab >> 3;
      int co = nt * 16 + (Lw & 15), ci = kh * 32 + (Lw >> 4) * 8 + j;
      wt3[i3] = f2bf(conv_w[co * 576 + ci * 9 + tap]);
    }
  }
}

// ---------------------------------------------------------------------------
// F2: fused q/k projection GEMMs — all weight B-frags now coalesced
// (frag-major); k-path A-frags staged via LDS (reusing Qs).
// q scale folds 0.25*log2(e) = 0.36067376.
// ---------------------------------------------------------------------------
__global__ __launch_bounds__(256) void fused_qk_gemm(
    const short* __restrict__ qt, const short* __restrict__ kt,
    const short* __restrict__ wt3, const short* __restrict__ wqb3,
    const short* __restrict__ wkb3,
    const float* __restrict__ nq_w, const float* __restrict__ nk_w,
    const float* __restrict__ bq, const float* __restrict__ bk,
    short* __restrict__ qp, short* __restrict__ kp) {
  __shared__ __align__(16) short Qs[164][72];   // q: halo tile / k: 64-row tile
  __shared__ __align__(16) short ln[4][16][80];
  const int blk = blockIdx.x;
  const int t = threadIdx.x;
  const int ws = t >> 6;
  const int L = t & 63;
  const int quad = L >> 4;
  const int l16 = L & 15;
  const short8 zero8 = {0, 0, 0, 0, 0, 0, 0, 0};

  if (blk < 288) {
    // ---- q path ----
    const int b = blk / 36;
    const int S0 = (blk % 36) * 64;
    const int sBase = S0 + ws * 16;
    const int s = sBase + l16;
    const int h = s / kW, w = s % kW;

    // stage rows [S0-49, S0+115) clamped; 164 rows x 8 int4 (coalesced)
    const short* qtb = qt + (size_t)b * kS * kC;
#pragma unroll
    for (int it = 0; it < 6; ++it) {
      int idx = it * 256 + t;
      if (idx < 164 * 8) {
        int r = idx >> 3, sg = idx & 7;
        int srow = S0 - 49 + r;
        srow = srow < 0 ? 0 : (srow >= kS ? kS - 1 : srow);
        *reinterpret_cast<int4*>(&Qs[r][sg * 8]) =
            *reinterpret_cast<const int4*>(qtb + (size_t)srow * kC + sg * 8);
      }
    }
    __syncthreads();

    const int baseLocal = ws * 16 + l16 + 49;
    f32x4 acc[4] = {{0.f, 0.f, 0.f, 0.f}, {0.f, 0.f, 0.f, 0.f},
                    {0.f, 0.f, 0.f, 0.f}, {0.f, 0.f, 0.f, 0.f}};
#pragma unroll
    for (int tap = 0; tap < 9; ++tap) {
      const int dh = tap / 3 - 1, dw = tap % 3 - 1;
      const bool valid = (unsigned)(h + dh) < (unsigned)kH &&
                         (unsigned)(w + dw) < (unsigned)kW;
      const int local = baseLocal + dh * kW + dw;
#pragma unroll
      for (int kh = 0; kh < 2; ++kh) {
        short8 af = *reinterpret_cast<const short8*>(&Qs[local][kh * 32 + quad * 8]);
        af = valid ? af : zero8;
        const short* wb = wt3 + ((tap * 2 + kh) * 4) * 512 + L * 8;
#pragma unroll
        for (int nt = 0; nt < 4; ++nt) {
          short8 bf = *reinterpret_cast<const short8*>(wb + nt * 512);  // coalesced
          acc[nt] = __builtin_amdgcn_mfma_f32_16x16x32_bf16(af, bf, acc[nt], 0, 0, 0);
        }
      }
    }
    float rstd[4];
#pragma unroll
    for (int reg = 0; reg < 4; ++reg) {
      float pr = acc[0][reg] * acc[0][reg] + acc[1][reg] * acc[1][reg]
               + acc[2][reg] * acc[2][reg] + acc[3][reg] * acc[3][reg];
      pr += __shfl_xor(pr, 1, 64);
      pr += __shfl_xor(pr, 2, 64);
      pr += __shfl_xor(pr, 4, 64);
      pr += __shfl_xor(pr, 8, 64);
      rstd[reg] = rsqrtf(pr * (1.0f / kC) + kEps);
    }
#pragma unroll
    for (int nt = 0; nt < 4; ++nt) {
      float g = nq_w[nt * 16 + l16];
#pragma unroll
      for (int reg = 0; reg < 4; ++reg) {
        ln[ws][quad * 4 + reg][nt * 16 + l16] = f2bf(acc[nt][reg] * rstd[reg] * g);
      }
    }
    __syncthreads();
    f32x4 acc2[4] = {{0.f, 0.f, 0.f, 0.f}, {0.f, 0.f, 0.f, 0.f},
                     {0.f, 0.f, 0.f, 0.f}, {0.f, 0.f, 0.f, 0.f}};
#pragma unroll
    for (int kh = 0; kh < 2; ++kh) {
      short8 af = *reinterpret_cast<const short8*>(&ln[ws][l16][kh * 32 + quad * 8]);
      const short* wb = wqb3 + (kh * 4) * 512 + L * 8;
#pragma unroll
      for (int nt = 0; nt < 4; ++nt) {
        short8 bf = *reinterpret_cast<const short8*>(wb + nt * 512);   // coalesced
        acc2[nt] = __builtin_amdgcn_mfma_f32_16x16x32_bf16(af, bf, acc2[nt], 0, 0, 0);
      }
    }
#pragma unroll
    for (int nt = 0; nt < 4; ++nt) {
      const int e = nt * 16 + l16;
      float bias = bq[e];
#pragma unroll
      for (int reg = 0; reg < 4; ++reg) {
        qp[((size_t)b * kS + sBase + quad * 4 + reg) * kC + e] =
            f2bf((acc2[nt][reg] + bias) * 0.36067376022224085f);
      }
    }
  } else {
    // ---- k path ----
    const int idx = blk - 288;
    const int b = idx / 36;
    const int S0 = (idx % 36) * 64;
    const int sBase = S0 + ws * 16;

    // stage 64 kt rows coalesced into Qs[0..63]
    const short* ktb = kt + ((size_t)b * kS + S0) * kC;
#pragma unroll
    for (int it = 0; it < 2; ++it) {
      int r = it * 32 + (t >> 3), sg = t & 7;
      *reinterpret_cast<int4*>(&Qs[r][sg * 8]) =
          *reinterpret_cast<const int4*>(ktb + (size_t)r * kC + sg * 8);
    }
    __syncthreads();

    short8 af0 = *reinterpret_cast<const short8*>(&Qs[ws * 16 + l16][quad * 8]);
    short8 af1 = *reinterpret_cast<const short8*>(&Qs[ws * 16 + l16][32 + quad * 8]);

    float xs[16];
#pragma unroll
    for (int j = 0; j < 8; ++j) { xs[j] = bf2f(af0[j]); xs[8 + j] = bf2f(af1[j]); }
    float sum = 0.f;
#pragma unroll
    for (int j = 0; j < 16; ++j) sum = fmaf(xs[j], xs[j], sum);
    sum += __shfl_xor(sum, 16, 64);
    sum += __shfl_xor(sum, 32, 64);
    float rstd = rsqrtf(sum * (1.0f / kC) + kEps);

    const float* n0 = nk_w + quad * 8;
#pragma unroll
    for (int j = 0; j < 8; ++j) {
      af0[j] = f2bf(xs[j] * rstd * n0[j]);
      af1[j] = f2bf(xs[8 + j] * rstd * n0[32 + j]);
    }

    f32x4 acc[4] = {{0.f, 0.f, 0.f, 0.f}, {0.f, 0.f, 0.f, 0.f},
                    {0.f, 0.f, 0.f, 0.f}, {0.f, 0.f, 0.f, 0.f}};
#pragma unroll
    for (int nt = 0; nt < 4; ++nt) {
      short8 bf0 = *reinterpret_cast<const short8*>(
          wkb3 + (0 * 4 + nt) * 512 + L * 8);   // coalesced
      short8 bf1 = *reinterpret_cast<const short8*>(
          wkb3 + (1 * 4 + nt) * 512 + L * 8);
      acc[nt] = __builtin_amdgcn_mfma_f32_16x16x32_bf16(af0, bf0, acc[nt], 0, 0, 0);
      acc[nt] = __builtin_amdgcn_mfma_f32_16x16x32_bf16(af1, bf1, acc[nt], 0, 0, 0);
    }
#pragma unroll
    for (int nt = 0; nt < 4; ++nt) {
      const int e = nt * 16 + l16;
      float bias = bk[e];
#pragma unroll
      for (int reg = 0; reg < 4; ++reg) {
        kp[((size_t)b * kS + sBase + quad * 4 + reg) * kC + e] =
            f2bf(acc[nt][reg] + bias);
      }
    }
  }
}

// ---------------------------------------------------------------------------
// K3: LDS-staged flash attention (unchanged from round 9 — register-capped at
// 4 blocks/CU by 64 AGPR acc + 64 arch VGPR; structure is at its floor).
// ---------------------------------------------------------------------------
__global__ __launch_bounds__(256, 4) void attn_flash(
    const short* __restrict__ qp, const short* __restrict__ kp,
    const short* __restrict__ vt, float* __restrict__ out) {
  __shared__ __align__(16) char pool[2 * 64 * 72 * 2 + 2 * 64 * 76 * 2]; // 37888
  __shared__ float pl[4][16][4];   // [ws][i][h]
  __shared__ float Li[16][4];      // 0.25 / l

  short (*Kt)[64][72] = reinterpret_cast<short (*)[64][72]>(pool);
  short (*Vt)[64][76] = reinterpret_cast<short (*)[64][76]>(pool + 2 * 64 * 72 * 2);
  float* slabF = reinterpret_cast<float*>(pool);   // epilogue alias

  const int blk = blockIdx.x;
  const int b = blk & 7;
  const int i0 = (blk >> 3) * 16;
  const int t = threadIdx.x;
  const int ws = t >> 6;           // j-quarter
  const int L = t & 63;
  const int quad = L >> 4;
  const int l16 = L & 15;

  const f32x4 zc = {0.f, 0.f, 0.f, 0.f};

  const short* qrow = qp + ((size_t)b * kS + i0 + l16) * kC + quad * 4;
  short4_t qh[4];
#pragma unroll
  for (int h = 0; h < 4; ++h)
    qh[h] = *reinterpret_cast<const short4_t*>(qrow + h * 16);

  const int r8i = t >> 3;   // 0..31
  const int seg = t & 7;
  const short* kg = kp + (size_t)b * kS * kC;
  const short* vg = vt + (size_t)b * kC * kS;

  int4 kreg[2], vreg[2];
#pragma unroll
  for (int pass = 0; pass < 2; ++pass) {
    kreg[pass] = *reinterpret_cast<const int4*>(
        kg + (size_t)(pass * 32 + r8i) * kC + seg * 8);
    vreg[pass] = *reinterpret_cast<const int4*>(
        vg + (size_t)(pass * 32 + r8i) * kS + seg * 8);
  }
#pragma unroll
  for (int pass = 0; pass < 2; ++pass) {
    *reinterpret_cast<int4*>(&Kt[0][pass * 32 + r8i][seg * 8]) = kreg[pass];
    *reinterpret_cast<int4*>(&Vt[0][pass * 32 + r8i][seg * 8]) = vreg[pass];
  }
  __syncthreads();

  f32x4 U[4][4];
#pragma unroll
  for (int h = 0; h < 4; ++h)
#pragma unroll
    for (int d = 0; d < 4; ++d) U[h][d] = zc;
  float lh[4] = {0.f, 0.f, 0.f, 0.f};

  for (int jt = 0; jt < kS / 64; ++jt) {
    const int buf = jt & 1;
    const bool more = (jt + 1) < kS / 64;
    if (more) {
      const int jn = (jt + 1) * 64;
#pragma unroll
      for (int pass = 0; pass < 2; ++pass) {
        kreg[pass] = *reinterpret_cast<const int4*>(
            kg + (size_t)(jn + pass * 32 + r8i) * kC + seg * 8);
        vreg[pass] = *reinterpret_cast<const int4*>(
            vg + (size_t)(pass * 32 + r8i) * kS + jn + seg * 8);
      }
    }

    short4_t kf[4], vf[4];
#pragma unroll
    for (int h = 0; h < 4; ++h)
      kf[h] = *reinterpret_cast<const short4_t*>(
          &Kt[buf][ws * 16 + l16][h * 16 + quad * 4]);
#pragma unroll
    for (int d = 0; d < 4; ++d)
      vf[d] = *reinterpret_cast<const short4_t*>(
          &Vt[buf][d * 16 + l16][ws * 16 + quad * 4]);

    short4_t p[4];
#pragma unroll
    for (int h = 0; h < 4; ++h) {
      f32x4 s = __builtin_amdgcn_mfma_f32_16x16x16bf16_1k(kf[h], qh[h], zc, 0, 0, 0);
      float e0 = exp2f(s[0]), e1 = exp2f(s[1]);
      float e2 = exp2f(s[2]), e3 = exp2f(s[3]);
      lh[h] += (e0 + e1) + (e2 + e3);
      union { __hip_bfloat162 h2[2]; short4_t s4; } cv;
      cv.h2[0] = __float22bfloat162_rn(make_float2(e0, e1));
      cv.h2[1] = __float22bfloat162_rn(make_float2(e2, e3));
      p[h] = cv.s4;
    }
#pragma unroll
    for (int h = 0; h < 4; ++h)
#pragma unroll
      for (int d = 0; d < 4; ++d)
        U[h][d] = __builtin_amdgcn_mfma_f32_16x16x16bf16_1k(vf[d], p[h], U[h][d], 0, 0, 0);

    if (more) {
      const int nb = buf ^ 1;
#pragma unroll
      for (int pass = 0; pass < 2; ++pass) {
        *reinterpret_cast<int4*>(&Kt[nb][pass * 32 + r8i][seg * 8]) = kreg[pass];
        *reinterpret_cast<int4*>(&Vt[nb][pass * 32 + r8i][seg * 8]) = vreg[pass];
      }
    }
    __syncthreads();
  }

  // ---- epilogue ----
#pragma unroll
  for (int h = 0; h < 4; ++h) {
    lh[h] += __shfl_xor(lh[h], 16, 64);
    lh[h] += __shfl_xor(lh[h], 32, 64);
  }
  if (quad == 0) {
#pragma unroll
    for (int h = 0; h < 4; ++h) pl[ws][l16][h] = lh[h];
  }
  __syncthreads();
  if (t < 64) {
    const int i = t >> 2, h = t & 3;
    Li[i][h] = 0.25f / (pl[0][i][h] + pl[1][i][h] + pl[2][i][h] + pl[3][i][h]);
  }
  __syncthreads();
  float c[4];
#pragma unroll
  for (int h = 0; h < 4; ++h) c[h] = Li[l16][h];

#pragma unroll
  for (int d = 0; d < 4; ++d) {
    if (ws != 0) {
      const int sid = ws - 1;
#pragma unroll
      for (int h = 0; h < 4; ++h)
#pragma unroll
        for (int reg = 0; reg < 4; ++reg)
          slabF[((sid * 4 + h) * 4 + reg) * 66 + L] = U[h][d][reg];
    }
    __syncthreads();
    if (ws == 0) {
      float of[4] = {0.f, 0.f, 0.f, 0.f};
#pragma unroll
      for (int h = 0; h < 4; ++h) {
#pragma unroll
        for (int reg = 0; reg < 4; ++reg) {
          float tot = U[h][d][reg]
                    + slabF[((0 * 4 + h) * 4 + reg) * 66 + L]
                    + slabF[((1 * 4 + h) * 4 + reg) * 66 + L]
                    + slabF[((2 * 4 + h) * 4 + reg) * 66 + L];
          of[reg] += tot * c[h];
        }
      }
      *reinterpret_cast<float4*>(
          out + ((size_t)b * kS + i0 + l16) * kC + d * 16 + quad * 4) =
          make_float4(of[0], of[1], of[2], of[3]);
    }
    __syncthreads();
  }
}

// ---------------------------------------------------------------------------
extern "C" void kernel_launch(void* const* d_in, const int* in_sizes, int n_in,
                              void* d_out, int out_size, void* d_ws, size_t ws_size,
                              hipStream_t stream) {
  const float* q      = (const float*)d_in[0];
  const float* k      = (const float*)d_in[1];
  const float* v      = (const float*)d_in[2];
  const float* conv_w = (const float*)d_in[3];
  const float* nq_w   = (const float*)d_in[4];
  const float* nk_w   = (const float*)d_in[5];
  const float* wq     = (const float*)d_in[6];
  const float* bq     = (const float*)d_in[7];
  const float* wk     = (const float*)d_in[8];
  const float* bk     = (const float*)d_in[9];
  float* out = (float*)d_out;

  const size_t N = (size_t)kB * kS * kC;   // 1,179,648
  short* qt   = (short*)d_ws;     // bf16 [b][s][c]
  short* kt   = qt + N;
  short* vt   = kt + N;           // bf16 [b][c][s]
  short* qp   = vt + N;           // bf16 [b][s][64]
  short* kp   = qp + N;
  short* wqb3 = kp + N;           // frag-major bf16
  short* wkb3 = wqb3 + 4096;
  short* wt3  = wkb3 + 4096;      // frag-major bf16 [72 slabs][512]

  fused_prep<<<1904, 256, 0, stream>>>(q, k, v, wq, wk, conv_w,
                                       qt, kt, vt, wqb3, wkb3, wt3);
  fused_qk_gemm<<<576, 256, 0, stream>>>(qt, kt, wt3, wqb3, wkb3,
                                         nq_w, nk_w, bq, bk, qp, kp);
  attn_flash<<<1152, 256, 0, stream>>>(qp, kp, vt, out);
}

// Round 11
// 162.687 us; speedup vs baseline: 1.6638x; 1.0853x over previous
//
#include <hip/hip_runtime.h>
#include <hip/hip_bf16.h>

namespace {
constexpr int kB = 8;
constexpr int kC = 64;
constexpr int kH = 48;
constexpr int kW = 48;
constexpr int kS = kH * kW;          // 2304
constexpr float kEps = 1.1920929e-07f;
}

typedef __attribute__((ext_vector_type(8))) short short8;   // 8 bf16 (4 VGPR)
typedef __attribute__((ext_vector_type(4))) short short4_t; // 4 bf16 (2 VGPR)
typedef __attribute__((ext_vector_type(4))) float f32x4;

// fp32 -> bf16 (round-nearest-even), bit-level
__device__ __forceinline__ short f2bf(float x) {
  unsigned u = __float_as_uint(x);
  u += 0x7fffu + ((u >> 16) & 1u);
  return (short)(u >> 16);
}
__device__ __forceinline__ float bf2f(short s) {
  return __uint_as_float(((unsigned)(unsigned short)s) << 16);
}

// ---------------------------------------------------------------------------
// F1: fused prep (identical to round 10: frag-major weight layouts).
// ---------------------------------------------------------------------------
__global__ __launch_bounds__(256) void fused_prep(
    const float* __restrict__ q, const float* __restrict__ k,
    const float* __restrict__ v, const float* __restrict__ wq,
    const float* __restrict__ wk, const float* __restrict__ conv_w,
    short* __restrict__ qt, short* __restrict__ kt, short* __restrict__ vt,
    short* __restrict__ wqb3, short* __restrict__ wkb3, short* __restrict__ wt3) {
  const int blk = blockIdx.x;
  if (blk < 576) {
    __shared__ float tile[64][65];
    const int zz = blk / 36;         // b*2 + which
    const int bx = blk % 36;
    const int b = zz >> 1;
    const float* src = (zz & 1) ? k : q;
    short* dst = (zz & 1) ? kt : qt;
    const int s0 = bx * 64;
    const int tx = threadIdx.x & 63;
    const int ty = threadIdx.x >> 6;
#pragma unroll
    for (int r = 0; r < 16; ++r) {
      int c = r * 4 + ty;
      tile[c][tx] = src[((size_t)b * kC + c) * kS + s0 + tx];
    }
    __syncthreads();
#pragma unroll
    for (int r = 0; r < 16; ++r) {
      int s = r * 4 + ty;
      dst[((size_t)b * kS + s0 + s) * kC + tx] = f2bf(tile[tx][s]);
    }
  } else if (blk < 1728) {
    int idx = ((blk - 576) * 256 + threadIdx.x) * 4;
    float4 x = *reinterpret_cast<const float4*>(v + idx);
    int2 o;
    o.x = ((int)(unsigned short)f2bf(x.y) << 16) | (unsigned short)f2bf(x.x);
    o.y = ((int)(unsigned short)f2bf(x.w) << 16) | (unsigned short)f2bf(x.z);
    *reinterpret_cast<int2*>(vt + idx) = o;
  } else {
    int idx = (blk - 1728) * 256 + threadIdx.x;
    if (idx < 4096) {
      int j = idx & 7, Lw = (idx >> 3) & 63, slab = idx >> 9;
      int nt = slab & 3, kh = slab >> 2;
      int e = nt * 16 + (Lw & 15), c = kh * 32 + (Lw >> 4) * 8 + j;
      wqb3[idx] = f2bf(wq[e * 64 + c]);
    } else if (idx < 8192) {
      int i2 = idx - 4096;
      int j = i2 & 7, Lw = (i2 >> 3) & 63, slab = i2 >> 9;
      int nt = slab & 3, kh = slab >> 2;
      int e = nt * 16 + (Lw & 15), c = kh * 32 + (Lw >> 4) * 8 + j;
      wkb3[i2] = f2bf(wk[e * 64 + c]);
    } else {
      int i3 = idx - 8192;   // < 36864
      int j = i3 & 7, Lw = (i3 >> 3) & 63, slab = i3 >> 9;   // 0..71
      int nt = slab & 3, kh = (slab >> 2) & 1, tap = slab >> 3;
      int co = nt * 16 + (Lw & 15), ci = kh * 32 + (Lw >> 4) * 8 + j;
      wt3[i3] = f2bf(conv_w[co * 576 + ci * 9 + tap]);
    }
  }
}

// ---------------------------------------------------------------------------
// F2: fused q/k projection GEMMs (round-10 structure; q scale back to 0.25
// since attention uses __expf again).
// ---------------------------------------------------------------------------
__global__ __launch_bounds__(256) void fused_qk_gemm(
    const short* __restrict__ qt, const short* __restrict__ kt,
    const short* __restrict__ wt3, const short* __restrict__ wqb3,
    const short* __restrict__ wkb3,
    const float* __restrict__ nq_w, const float* __restrict__ nk_w,
    const float* __restrict__ bq, const float* __restrict__ bk,
    short* __restrict__ qp, short* __restrict__ kp) {
  __shared__ __align__(16) short Qs[164][72];   // q: halo tile / k: 64-row tile
  __shared__ __align__(16) short ln[4][16][80];
  const int blk = blockIdx.x;
  const int t = threadIdx.x;
  const int ws = t >> 6;
  const int L = t & 63;
  const int quad = L >> 4;
  const int l16 = L & 15;
  const short8 zero8 = {0, 0, 0, 0, 0, 0, 0, 0};

  if (blk < 288) {
    // ---- q path ----
    const int b = blk / 36;
    const int S0 = (blk % 36) * 64;
    const int sBase = S0 + ws * 16;
    const int s = sBase + l16;
    const int h = s / kW, w = s % kW;

    const short* qtb = qt + (size_t)b * kS * kC;
#pragma unroll
    for (int it = 0; it < 6; ++it) {
      int idx = it * 256 + t;
      if (idx < 164 * 8) {
        int r = idx >> 3, sg = idx & 7;
        int srow = S0 - 49 + r;
        srow = srow < 0 ? 0 : (srow >= kS ? kS - 1 : srow);
        *reinterpret_cast<int4*>(&Qs[r][sg * 8]) =
            *reinterpret_cast<const int4*>(qtb + (size_t)srow * kC + sg * 8);
      }
    }
    __syncthreads();

    const int baseLocal = ws * 16 + l16 + 49;
    f32x4 acc[4] = {{0.f, 0.f, 0.f, 0.f}, {0.f, 0.f, 0.f, 0.f},
                    {0.f, 0.f, 0.f, 0.f}, {0.f, 0.f, 0.f, 0.f}};
#pragma unroll
    for (int tap = 0; tap < 9; ++tap) {
      const int dh = tap / 3 - 1, dw = tap % 3 - 1;
      const bool valid = (unsigned)(h + dh) < (unsigned)kH &&
                         (unsigned)(w + dw) < (unsigned)kW;
      const int local = baseLocal + dh * kW + dw;
#pragma unroll
      for (int kh = 0; kh < 2; ++kh) {
        short8 af = *reinterpret_cast<const short8*>(&Qs[local][kh * 32 + quad * 8]);
        af = valid ? af : zero8;
        const short* wb = wt3 + ((tap * 2 + kh) * 4) * 512 + L * 8;
#pragma unroll
        for (int nt = 0; nt < 4; ++nt) {
          short8 bf = *reinterpret_cast<const short8*>(wb + nt * 512);  // coalesced
          acc[nt] = __builtin_amdgcn_mfma_f32_16x16x32_bf16(af, bf, acc[nt], 0, 0, 0);
        }
      }
    }
    float rstd[4];
#pragma unroll
    for (int reg = 0; reg < 4; ++reg) {
      float pr = acc[0][reg] * acc[0][reg] + acc[1][reg] * acc[1][reg]
               + acc[2][reg] * acc[2][reg] + acc[3][reg] * acc[3][reg];
      pr += __shfl_xor(pr, 1, 64);
      pr += __shfl_xor(pr, 2, 64);
      pr += __shfl_xor(pr, 4, 64);
      pr += __shfl_xor(pr, 8, 64);
      rstd[reg] = rsqrtf(pr * (1.0f / kC) + kEps);
    }
#pragma unroll
    for (int nt = 0; nt < 4; ++nt) {
      float g = nq_w[nt * 16 + l16];
#pragma unroll
      for (int reg = 0; reg < 4; ++reg) {
        ln[ws][quad * 4 + reg][nt * 16 + l16] = f2bf(acc[nt][reg] * rstd[reg] * g);
      }
    }
    __syncthreads();
    f32x4 acc2[4] = {{0.f, 0.f, 0.f, 0.f}, {0.f, 0.f, 0.f, 0.f},
                     {0.f, 0.f, 0.f, 0.f}, {0.f, 0.f, 0.f, 0.f}};
#pragma unroll
    for (int kh = 0; kh < 2; ++kh) {
      short8 af = *reinterpret_cast<const short8*>(&ln[ws][l16][kh * 32 + quad * 8]);
      const short* wb = wqb3 + (kh * 4) * 512 + L * 8;
#pragma unroll
      for (int nt = 0; nt < 4; ++nt) {
        short8 bf = *reinterpret_cast<const short8*>(wb + nt * 512);   // coalesced
        acc2[nt] = __builtin_amdgcn_mfma_f32_16x16x32_bf16(af, bf, acc2[nt], 0, 0, 0);
      }
    }
#pragma unroll
    for (int nt = 0; nt < 4; ++nt) {
      const int e = nt * 16 + l16;
      float bias = bq[e];
#pragma unroll
      for (int reg = 0; reg < 4; ++reg) {
        qp[((size_t)b * kS + sBase + quad * 4 + reg) * kC + e] =
            f2bf((acc2[nt][reg] + bias) * 0.25f);
      }
    }
  } else {
    // ---- k path ----
    const int idx = blk - 288;
    const int b = idx / 36;
    const int S0 = (idx % 36) * 64;
    const int sBase = S0 + ws * 16;

    const short* ktb = kt + ((size_t)b * kS + S0) * kC;
#pragma unroll
    for (int it = 0; it < 2; ++it) {
      int r = it * 32 + (t >> 3), sg = t & 7;
      *reinterpret_cast<int4*>(&Qs[r][sg * 8]) =
          *reinterpret_cast<const int4*>(ktb + (size_t)r * kC + sg * 8);
    }
    __syncthreads();

    short8 af0 = *reinterpret_cast<const short8*>(&Qs[ws * 16 + l16][quad * 8]);
    short8 af1 = *reinterpret_cast<const short8*>(&Qs[ws * 16 + l16][32 + quad * 8]);

    float xs[16];
#pragma unroll
    for (int j = 0; j < 8; ++j) { xs[j] = bf2f(af0[j]); xs[8 + j] = bf2f(af1[j]); }
    float sum = 0.f;
#pragma unroll
    for (int j = 0; j < 16; ++j) sum = fmaf(xs[j], xs[j], sum);
    sum += __shfl_xor(sum, 16, 64);
    sum += __shfl_xor(sum, 32, 64);
    float rstd = rsqrtf(sum * (1.0f / kC) + kEps);

    const float* n0 = nk_w + quad * 8;
#pragma unroll
    for (int j = 0; j < 8; ++j) {
      af0[j] = f2bf(xs[j] * rstd * n0[j]);
      af1[j] = f2bf(xs[8 + j] * rstd * n0[32 + j]);
    }

    f32x4 acc[4] = {{0.f, 0.f, 0.f, 0.f}, {0.f, 0.f, 0.f, 0.f},
                    {0.f, 0.f, 0.f, 0.f}, {0.f, 0.f, 0.f, 0.f}};
#pragma unroll
    for (int nt = 0; nt < 4; ++nt) {
      short8 bf0 = *reinterpret_cast<const short8*>(
          wkb3 + (0 * 4 + nt) * 512 + L * 8);
      short8 bf1 = *reinterpret_cast<const short8*>(
          wkb3 + (1 * 4 + nt) * 512 + L * 8);
      acc[nt] = __builtin_amdgcn_mfma_f32_16x16x32_bf16(af0, bf0, acc[nt], 0, 0, 0);
      acc[nt] = __builtin_amdgcn_mfma_f32_16x16x32_bf16(af1, bf1, acc[nt], 0, 0, 0);
    }
#pragma unroll
    for (int nt = 0; nt < 4; ++nt) {
      const int e = nt * 16 + l16;
      float bias = bk[e];
#pragma unroll
      for (int reg = 0; reg < 4; ++reg) {
        kp[((size_t)b * kS + sBase + quad * 4 + reg) * kC + e] =
            f2bf(acc[nt][reg] + bias);
      }
    }
  }
}

// ---------------------------------------------------------------------------
// K3: flash attention on K=32 MFMAs (16x16x16 is quarter-rate on gfx950!).
// grid 576: b = blk&7, i0 = (blk>>3)*32. 4 waves = (isub, jhalf): wave handles
// 16 i x 32 j of each 64-j tile. Per tile:
//   - QK: S^T_h = mfma32(A=K window, B=Q masked-per-head) (r6-verified masking)
//   - exp via __expf; P packed bf16 into wave-private LDS p-tile (b64 writes,
//     in-order DS, no barrier), re-read as B-frag (b128)
//   - PV: U_h^T[dtile] += mfma32(A=V^T, B=P^T), K spans the wave's 32 j's
// Staging double-buffered, one barrier/tile. Epilogue: jhalf-pair reduce.
// ---------------------------------------------------------------------------
__global__ __launch_bounds__(256, 3) void attn_flash(
    const short* __restrict__ qp, const short* __restrict__ kp,
    const short* __restrict__ vt, float* __restrict__ out) {
  __shared__ __align__(16) short Kt[2][64][72];
  __shared__ __align__(16) short Vt[2][64][72];
  __shared__ __align__(16) short ptile[4][16][40];  // per-wave P round-trip
  __shared__ float pl[4][16][4];   // [ws][i16][h]
  __shared__ float Li[32][4];      // 0.25 / l

  float* slabF = reinterpret_cast<float*>(&Kt[0][0][0]);  // epilogue alias

  const int blk = blockIdx.x;
  const int b = blk & 7;
  const int i0 = (blk >> 3) * 32;
  const int t = threadIdx.x;
  const int ws = t >> 6;
  const int isub = ws & 1;
  const int jhalf = ws >> 1;
  const int jbase = jhalf * 32;
  const int L = t & 63;
  const int quad = L >> 4;
  const int l16 = L & 15;

  const f32x4 zc = {0.f, 0.f, 0.f, 0.f};
  const short8 z8 = {0, 0, 0, 0, 0, 0, 0, 0};

  // Q windows (B operand, K=32): row i = i0+isub*16+l16, dims quad*8..+7 (+32)
  const short* qrow = qp + ((size_t)b * kS + i0 + isub * 16 + l16) * kC;
  const short8 qw0 = *reinterpret_cast<const short8*>(qrow + quad * 8);
  const short8 qw1 = *reinterpret_cast<const short8*>(qrow + 32 + quad * 8);
  const bool lo = quad < 2;
  const short8 qm[4] = {lo ? qw0 : z8, lo ? z8 : qw0,
                        lo ? qw1 : z8, lo ? z8 : qw1};

  // staging: octet covers one 128B row; 2 passes of 32 rows
  const int r8i = t >> 3;   // 0..31
  const int seg = t & 7;
  const short* kg = kp + (size_t)b * kS * kC;
  const short* vg = vt + (size_t)b * kC * kS;

  int4 kreg[2], vreg[2];
#pragma unroll
  for (int pass = 0; pass < 2; ++pass) {
    kreg[pass] = *reinterpret_cast<const int4*>(
        kg + (size_t)(pass * 32 + r8i) * kC + seg * 8);
    vreg[pass] = *reinterpret_cast<const int4*>(
        vg + (size_t)(pass * 32 + r8i) * kS + seg * 8);
  }
#pragma unroll
  for (int pass = 0; pass < 2; ++pass) {
    *reinterpret_cast<int4*>(&Kt[0][pass * 32 + r8i][seg * 8]) = kreg[pass];
    *reinterpret_cast<int4*>(&Vt[0][pass * 32 + r8i][seg * 8]) = vreg[pass];
  }
  __syncthreads();

  f32x4 U[4][4];   // [h][dtile]: lane holds d=dtile*16+quad*4+reg, i=l16
#pragma unroll
  for (int h = 0; h < 4; ++h)
#pragma unroll
    for (int d = 0; d < 4; ++d) U[h][d] = zc;
  float lh[4] = {0.f, 0.f, 0.f, 0.f};

  for (int jt = 0; jt < kS / 64; ++jt) {
    const int buf = jt & 1;
    const bool more = (jt + 1) < kS / 64;
    if (more) {
      const int jn = (jt + 1) * 64;
#pragma unroll
      for (int pass = 0; pass < 2; ++pass) {
        kreg[pass] = *reinterpret_cast<const int4*>(
            kg + (size_t)(jn + pass * 32 + r8i) * kC + seg * 8);
        vreg[pass] = *reinterpret_cast<const int4*>(
            vg + (size_t)(pass * 32 + r8i) * kS + jn + seg * 8);
      }
    }

    // K A-frags: [chunk][window]; V^T A-frags per dtile (K spans wave's 32 j)
    short8 kf[2][2];
#pragma unroll
    for (int c = 0; c < 2; ++c)
#pragma unroll
      for (int w = 0; w < 2; ++w)
        kf[c][w] = *reinterpret_cast<const short8*>(
            &Kt[buf][jbase + c * 16 + l16][w * 32 + quad * 8]);
    short8 vf[4];
#pragma unroll
    for (int d = 0; d < 4; ++d)
      vf[d] = *reinterpret_cast<const short8*>(
          &Vt[buf][d * 16 + l16][jbase + quad * 8]);

#pragma unroll
    for (int h = 0; h < 4; ++h) {
      const int w = h >> 1;
      // S^T_h for both 16-j chunks: lane: j_loc = c*16+quad*4+reg, i = l16
      f32x4 s0 = __builtin_amdgcn_mfma_f32_16x16x32_bf16(kf[0][w], qm[h], zc, 0, 0, 0);
      f32x4 s1 = __builtin_amdgcn_mfma_f32_16x16x32_bf16(kf[1][w], qm[h], zc, 0, 0, 0);
      float e0 = __expf(s0[0]), e1 = __expf(s0[1]);
      float e2 = __expf(s0[2]), e3 = __expf(s0[3]);
      float f0 = __expf(s1[0]), f1 = __expf(s1[1]);
      float f2 = __expf(s1[2]), f3 = __expf(s1[3]);
      lh[h] += ((e0 + e1) + (e2 + e3)) + ((f0 + f1) + (f2 + f3));
      union { __hip_bfloat162 h2[2]; short4_t s4; } ca, cb;
      ca.h2[0] = __float22bfloat162_rn(make_float2(e0, e1));
      ca.h2[1] = __float22bfloat162_rn(make_float2(e2, e3));
      cb.h2[0] = __float22bfloat162_rn(make_float2(f0, f1));
      cb.h2[1] = __float22bfloat162_rn(make_float2(f2, f3));
      // P[i=l16][j_loc]: chunk0 at col quad*4, chunk1 at col 16+quad*4
      *reinterpret_cast<short4_t*>(&ptile[ws][l16][quad * 4]) = ca.s4;
      *reinterpret_cast<short4_t*>(&ptile[ws][l16][16 + quad * 4]) = cb.s4;
      // B-frag read: P^T[k=quad*8+idx][n=l16]  (in-order DS: safe, no barrier)
      short8 pf = *reinterpret_cast<const short8*>(&ptile[ws][l16][quad * 8]);
#pragma unroll
      for (int d = 0; d < 4; ++d)
        U[h][d] = __builtin_amdgcn_mfma_f32_16x16x32_bf16(vf[d], pf, U[h][d], 0, 0, 0);
    }

    if (more) {
      const int nb = buf ^ 1;
#pragma unroll
      for (int pass = 0; pass < 2; ++pass) {
        *reinterpret_cast<int4*>(&Kt[nb][pass * 32 + r8i][seg * 8]) = kreg[pass];
        *reinterpret_cast<int4*>(&Vt[nb][pass * 32 + r8i][seg * 8]) = vreg[pass];
      }
    }
    __syncthreads();
  }

  // ---- epilogue ----
#pragma unroll
  for (int h = 0; h < 4; ++h) {
    lh[h] += __shfl_xor(lh[h], 16, 64);
    lh[h] += __shfl_xor(lh[h], 32, 64);
  }
  if (quad == 0) {
#pragma unroll
    for (int h = 0; h < 4; ++h) pl[ws][l16][h] = lh[h];
  }
  __syncthreads();
  if (t < 128) {
    const int i = t >> 2, h = t & 3;    // i 0..31 (global sub-row)
    Li[i][h] = 0.25f / (pl[i >> 4][i & 15][h] + pl[(i >> 4) + 2][i & 15][h]);
  }
  __syncthreads();
  float c[4];
#pragma unroll
  for (int h = 0; h < 4; ++h) c[h] = Li[isub * 16 + l16][h];

  // jhalf-pair reduce, one d-tile per phase; slab lane-major (stride 66)
#pragma unroll
  for (int d = 0; d < 4; ++d) {
    if (jhalf == 1) {
#pragma unroll
      for (int h = 0; h < 4; ++h)
#pragma unroll
        for (int reg = 0; reg < 4; ++reg)
          slabF[((isub * 4 + h) * 4 + reg) * 66 + L] = U[h][d][reg];
    }
    __syncthreads();
    if (jhalf == 0) {
      float of[4] = {0.f, 0.f, 0.f, 0.f};
#pragma unroll
      for (int h = 0; h < 4; ++h) {
#pragma unroll
        for (int reg = 0; reg < 4; ++reg) {
          float tot = U[h][d][reg] + slabF[((isub * 4 + h) * 4 + reg) * 66 + L];
          of[reg] += tot * c[h];
        }
      }
      *reinterpret_cast<float4*>(
          out + ((size_t)b * kS + i0 + isub * 16 + l16) * kC + d * 16 + quad * 4) =
          make_float4(of[0], of[1], of[2], of[3]);
    }
    __syncthreads();
  }
}

// ---------------------------------------------------------------------------
extern "C" void kernel_launch(void* const* d_in, const int* in_sizes, int n_in,
                              void* d_out, int out_size, void* d_ws, size_t ws_size,
                              hipStream_t stream) {
  const float* q      = (const float*)d_in[0];
  const float* k      = (const float*)d_in[1];
  const float* v      = (const float*)d_in[2];
  const float* conv_w = (const float*)d_in[3];
  const float* nq_w   = (const float*)d_in[4];
  const float* nk_w   = (const float*)d_in[5];
  const float* wq     = (const float*)d_in[6];
  const float* bq     = (const float*)d_in[7];
  const float* wk     = (const float*)d_in[8];
  const float* bk     = (const float*)d_in[9];
  float* out = (float*)d_out;

  const size_t N = (size_t)kB * kS * kC;   // 1,179,648
  short* qt   = (short*)d_ws;     // bf16 [b][s][c]
  short* kt   = qt + N;
  short* vt   = kt + N;           // bf16 [b][c][s]
  short* qp   = vt + N;           // bf16 [b][s][64]
  short* kp   = qp + N;
  short* wqb3 = kp + N;           // frag-major bf16
  short* wkb3 = wqb3 + 4096;
  short* wt3  = wkb3 + 4096;      // frag-major bf16 [72 slabs][512]

  fused_prep<<<1904, 256, 0, stream>>>(q, k, v, wq, wk, conv_w,
                                       qt, kt, vt, wqb3, wkb3, wt3);
  fused_qk_gemm<<<576, 256, 0, stream>>>(qt, kt, wt3, wqb3, wkb3,
                                         nq_w, nk_w, bq, bk, qp, kp);
  attn_flash<<<576, 256, 0, stream>>>(qp, kp, vt, out);
}

// Round 12
// 155.622 us; speedup vs baseline: 1.7393x; 1.0454x over previous
//
#include <hip/hip_runtime.h>
#include <hip/hip_bf16.h>

namespace {
constexpr int kB = 8;
constexpr int kC = 64;
constexpr int kH = 48;
constexpr int kW = 48;
constexpr int kS = kH * kW;          // 2304
constexpr float kEps = 1.1920929e-07f;
}

typedef __attribute__((ext_vector_type(8))) short short8;   // 8 bf16 (4 VGPR)
typedef __attribute__((ext_vector_type(4))) short short4_t; // 4 bf16 (2 VGPR)
typedef __attribute__((ext_vector_type(4))) float f32x4;

// fp32 -> bf16 (round-nearest-even), bit-level
__device__ __forceinline__ short f2bf(float x) {
  unsigned u = __float_as_uint(x);
  u += 0x7fffu + ((u >> 16) & 1u);
  return (short)(u >> 16);
}
__device__ __forceinline__ float bf2f(short s) {
  return __uint_as_float(((unsigned)(unsigned short)s) << 16);
}

// ---------------------------------------------------------------------------
// F1: fused prep (identical to round 10: frag-major weight layouts).
// ---------------------------------------------------------------------------
__global__ __launch_bounds__(256) void fused_prep(
    const float* __restrict__ q, const float* __restrict__ k,
    const float* __restrict__ v, const float* __restrict__ wq,
    const float* __restrict__ wk, const float* __restrict__ conv_w,
    short* __restrict__ qt, short* __restrict__ kt, short* __restrict__ vt,
    short* __restrict__ wqb3, short* __restrict__ wkb3, short* __restrict__ wt3) {
  const int blk = blockIdx.x;
  if (blk < 576) {
    __shared__ float tile[64][65];
    const int zz = blk / 36;         // b*2 + which
    const int bx = blk % 36;
    const int b = zz >> 1;
    const float* src = (zz & 1) ? k : q;
    short* dst = (zz & 1) ? kt : qt;
    const int s0 = bx * 64;
    const int tx = threadIdx.x & 63;
    const int ty = threadIdx.x >> 6;
#pragma unroll
    for (int r = 0; r < 16; ++r) {
      int c = r * 4 + ty;
      tile[c][tx] = src[((size_t)b * kC + c) * kS + s0 + tx];
    }
    __syncthreads();
#pragma unroll
    for (int r = 0; r < 16; ++r) {
      int s = r * 4 + ty;
      dst[((size_t)b * kS + s0 + s) * kC + tx] = f2bf(tile[tx][s]);
    }
  } else if (blk < 1728) {
    int idx = ((blk - 576) * 256 + threadIdx.x) * 4;
    float4 x = *reinterpret_cast<const float4*>(v + idx);
    int2 o;
    o.x = ((int)(unsigned short)f2bf(x.y) << 16) | (unsigned short)f2bf(x.x);
    o.y = ((int)(unsigned short)f2bf(x.w) << 16) | (unsigned short)f2bf(x.z);
    *reinterpret_cast<int2*>(vt + idx) = o;
  } else {
    int idx = (blk - 1728) * 256 + threadIdx.x;
    if (idx < 4096) {
      int j = idx & 7, Lw = (idx >> 3) & 63, slab = idx >> 9;
      int nt = slab & 3, kh = slab >> 2;
      int e = nt * 16 + (Lw & 15), c = kh * 32 + (Lw >> 4) * 8 + j;
      wqb3[idx] = f2bf(wq[e * 64 + c]);
    } else if (idx < 8192) {
      int i2 = idx - 4096;
      int j = i2 & 7, Lw = (i2 >> 3) & 63, slab = i2 >> 9;
      int nt = slab & 3, kh = slab >> 2;
      int e = nt * 16 + (Lw & 15), c = kh * 32 + (Lw >> 4) * 8 + j;
      wkb3[i2] = f2bf(wk[e * 64 + c]);
    } else {
      int i3 = idx - 8192;   // < 36864
      int j = i3 & 7, Lw = (i3 >> 3) & 63, slab = i3 >> 9;   // 0..71
      int nt = slab & 3, kh = (slab >> 2) & 1, tap = slab >> 3;
      int co = nt * 16 + (Lw & 15), ci = kh * 32 + (Lw >> 4) * 8 + j;
      wt3[i3] = f2bf(conv_w[co * 576 + ci * 9 + tap]);
    }
  }
}

// ---------------------------------------------------------------------------
// F2: fused q/k projection GEMMs (unchanged from round 11).
// ---------------------------------------------------------------------------
__global__ __launch_bounds__(256) void fused_qk_gemm(
    const short* __restrict__ qt, const short* __restrict__ kt,
    const short* __restrict__ wt3, const short* __restrict__ wqb3,
    const short* __restrict__ wkb3,
    const float* __restrict__ nq_w, const float* __restrict__ nk_w,
    const float* __restrict__ bq, const float* __restrict__ bk,
    short* __restrict__ qp, short* __restrict__ kp) {
  __shared__ __align__(16) short Qs[164][72];   // q: halo tile / k: 64-row tile
  __shared__ __align__(16) short ln[4][16][80];
  const int blk = blockIdx.x;
  const int t = threadIdx.x;
  const int ws = t >> 6;
  const int L = t & 63;
  const int quad = L >> 4;
  const int l16 = L & 15;
  const short8 zero8 = {0, 0, 0, 0, 0, 0, 0, 0};

  if (blk < 288) {
    // ---- q path ----
    const int b = blk / 36;
    const int S0 = (blk % 36) * 64;
    const int sBase = S0 + ws * 16;
    const int s = sBase + l16;
    const int h = s / kW, w = s % kW;

    const short* qtb = qt + (size_t)b * kS * kC;
#pragma unroll
    for (int it = 0; it < 6; ++it) {
      int idx = it * 256 + t;
      if (idx < 164 * 8) {
        int r = idx >> 3, sg = idx & 7;
        int srow = S0 - 49 + r;
        srow = srow < 0 ? 0 : (srow >= kS ? kS - 1 : srow);
        *reinterpret_cast<int4*>(&Qs[r][sg * 8]) =
            *reinterpret_cast<const int4*>(qtb + (size_t)srow * kC + sg * 8);
      }
    }
    __syncthreads();

    const int baseLocal = ws * 16 + l16 + 49;
    f32x4 acc[4] = {{0.f, 0.f, 0.f, 0.f}, {0.f, 0.f, 0.f, 0.f},
                    {0.f, 0.f, 0.f, 0.f}, {0.f, 0.f, 0.f, 0.f}};
#pragma unroll
    for (int tap = 0; tap < 9; ++tap) {
      const int dh = tap / 3 - 1, dw = tap % 3 - 1;
      const bool valid = (unsigned)(h + dh) < (unsigned)kH &&
                         (unsigned)(w + dw) < (unsigned)kW;
      const int local = baseLocal + dh * kW + dw;
#pragma unroll
      for (int kh = 0; kh < 2; ++kh) {
        short8 af = *reinterpret_cast<const short8*>(&Qs[local][kh * 32 + quad * 8]);
        af = valid ? af : zero8;
        const short* wb = wt3 + ((tap * 2 + kh) * 4) * 512 + L * 8;
#pragma unroll
        for (int nt = 0; nt < 4; ++nt) {
          short8 bf = *reinterpret_cast<const short8*>(wb + nt * 512);  // coalesced
          acc[nt] = __builtin_amdgcn_mfma_f32_16x16x32_bf16(af, bf, acc[nt], 0, 0, 0);
        }
      }
    }
    float rstd[4];
#pragma unroll
    for (int reg = 0; reg < 4; ++reg) {
      float pr = acc[0][reg] * acc[0][reg] + acc[1][reg] * acc[1][reg]
               + acc[2][reg] * acc[2][reg] + acc[3][reg] * acc[3][reg];
      pr += __shfl_xor(pr, 1, 64);
      pr += __shfl_xor(pr, 2, 64);
      pr += __shfl_xor(pr, 4, 64);
      pr += __shfl_xor(pr, 8, 64);
      rstd[reg] = rsqrtf(pr * (1.0f / kC) + kEps);
    }
#pragma unroll
    for (int nt = 0; nt < 4; ++nt) {
      float g = nq_w[nt * 16 + l16];
#pragma unroll
      for (int reg = 0; reg < 4; ++reg) {
        ln[ws][quad * 4 + reg][nt * 16 + l16] = f2bf(acc[nt][reg] * rstd[reg] * g);
      }
    }
    __syncthreads();
    f32x4 acc2[4] = {{0.f, 0.f, 0.f, 0.f}, {0.f, 0.f, 0.f, 0.f},
                     {0.f, 0.f, 0.f, 0.f}, {0.f, 0.f, 0.f, 0.f}};
#pragma unroll
    for (int kh = 0; kh < 2; ++kh) {
      short8 af = *reinterpret_cast<const short8*>(&ln[ws][l16][kh * 32 + quad * 8]);
      const short* wb = wqb3 + (kh * 4) * 512 + L * 8;
#pragma unroll
      for (int nt = 0; nt < 4; ++nt) {
        short8 bf = *reinterpret_cast<const short8*>(wb + nt * 512);   // coalesced
        acc2[nt] = __builtin_amdgcn_mfma_f32_16x16x32_bf16(af, bf, acc2[nt], 0, 0, 0);
      }
    }
#pragma unroll
    for (int nt = 0; nt < 4; ++nt) {
      const int e = nt * 16 + l16;
      float bias = bq[e];
#pragma unroll
      for (int reg = 0; reg < 4; ++reg) {
        qp[((size_t)b * kS + sBase + quad * 4 + reg) * kC + e] =
            f2bf((acc2[nt][reg] + bias) * 0.25f);
      }
    }
  } else {
    // ---- k path ----
    const int idx = blk - 288;
    const int b = idx / 36;
    const int S0 = (idx % 36) * 64;
    const int sBase = S0 + ws * 16;

    const short* ktb = kt + ((size_t)b * kS + S0) * kC;
#pragma unroll
    for (int it = 0; it < 2; ++it) {
      int r = it * 32 + (t >> 3), sg = t & 7;
      *reinterpret_cast<int4*>(&Qs[r][sg * 8]) =
          *reinterpret_cast<const int4*>(ktb + (size_t)r * kC + sg * 8);
    }
    __syncthreads();

    short8 af0 = *reinterpret_cast<const short8*>(&Qs[ws * 16 + l16][quad * 8]);
    short8 af1 = *reinterpret_cast<const short8*>(&Qs[ws * 16 + l16][32 + quad * 8]);

    float xs[16];
#pragma unroll
    for (int j = 0; j < 8; ++j) { xs[j] = bf2f(af0[j]); xs[8 + j] = bf2f(af1[j]); }
    float sum = 0.f;
#pragma unroll
    for (int j = 0; j < 16; ++j) sum = fmaf(xs[j], xs[j], sum);
    sum += __shfl_xor(sum, 16, 64);
    sum += __shfl_xor(sum, 32, 64);
    float rstd = rsqrtf(sum * (1.0f / kC) + kEps);

    const float* n0 = nk_w + quad * 8;
#pragma unroll
    for (int j = 0; j < 8; ++j) {
      af0[j] = f2bf(xs[j] * rstd * n0[j]);
      af1[j] = f2bf(xs[8 + j] * rstd * n0[32 + j]);
    }

    f32x4 acc[4] = {{0.f, 0.f, 0.f, 0.f}, {0.f, 0.f, 0.f, 0.f},
                    {0.f, 0.f, 0.f, 0.f}, {0.f, 0.f, 0.f, 0.f}};
#pragma unroll
    for (int nt = 0; nt < 4; ++nt) {
      short8 bf0 = *reinterpret_cast<const short8*>(
          wkb3 + (0 * 4 + nt) * 512 + L * 8);
      short8 bf1 = *reinterpret_cast<const short8*>(
          wkb3 + (1 * 4 + nt) * 512 + L * 8);
      acc[nt] = __builtin_amdgcn_mfma_f32_16x16x32_bf16(af0, bf0, acc[nt], 0, 0, 0);
      acc[nt] = __builtin_amdgcn_mfma_f32_16x16x32_bf16(af1, bf1, acc[nt], 0, 0, 0);
    }
#pragma unroll
    for (int nt = 0; nt < 4; ++nt) {
      const int e = nt * 16 + l16;
      float bias = bk[e];
#pragma unroll
      for (int reg = 0; reg < 4; ++reg) {
        kp[((size_t)b * kS + sBase + quad * 4 + reg) * kC + e] =
            f2bf(acc[nt][reg] + bias);
      }
    }
  }
}

// ---------------------------------------------------------------------------
// K3: flash attention, K=32 MFMAs, ZERO-LDS P transpose via K-row permutation.
// Staging writes K row (source offset j = q*8 + c*4 + r within each 32-row
// group) to LDS tile position p = c*16 + q*4 + r. Then the two QK S^T MFMAs
// (chunks c=0,1) leave lane `quad` holding e(i=l16, j=quad*8+0..7) — exactly
// the PV B-operand fragment. P never touches LDS. V tile is unpermuted (its
// A-operand enumerates k as quad*8+idx over original j — matches).
// grid 576: b = blk&7, i0 = (blk>>3)*32; 4 waves = (isub, jhalf).
// ---------------------------------------------------------------------------
__global__ __launch_bounds__(256, 3) void attn_flash(
    const short* __restrict__ qp, const short* __restrict__ kp,
    const short* __restrict__ vt, float* __restrict__ out) {
  __shared__ __align__(16) short Kt[2][64][72];   // K rows PERMUTED per 32-group
  __shared__ __align__(16) short Vt[2][64][72];   // V^T rows, unpermuted
  __shared__ float pl[4][16][4];   // [ws][i16][h]
  __shared__ float Li[32][4];      // 0.25 / l

  float* slabF = reinterpret_cast<float*>(&Kt[0][0][0]);  // epilogue alias

  const int blk = blockIdx.x;
  const int b = blk & 7;
  const int i0 = (blk >> 3) * 32;
  const int t = threadIdx.x;
  const int ws = t >> 6;
  const int isub = ws & 1;
  const int jhalf = ws >> 1;
  const int jbase = jhalf * 32;
  const int L = t & 63;
  const int quad = L >> 4;
  const int l16 = L & 15;

  const f32x4 zc = {0.f, 0.f, 0.f, 0.f};
  const short8 z8 = {0, 0, 0, 0, 0, 0, 0, 0};

  // Q windows (B operand, K=32): row i = i0+isub*16+l16, dims quad*8..+7 (+32)
  const short* qrow = qp + ((size_t)b * kS + i0 + isub * 16 + l16) * kC;
  const short8 qw0 = *reinterpret_cast<const short8*>(qrow + quad * 8);
  const short8 qw1 = *reinterpret_cast<const short8*>(qrow + 32 + quad * 8);
  const bool lo = quad < 2;
  const short8 qm[4] = {lo ? qw0 : z8, lo ? z8 : qw0,
                        lo ? qw1 : z8, lo ? z8 : qw1};

  // staging geometry: octet covers one 128B row; 2 passes of 32 rows.
  const int r8i = t >> 3;   // 0..31
  const int seg = t & 7;
  const short* kg = kp + (size_t)b * kS * kC;
  const short* vg = vt + (size_t)b * kC * kS;

  // K destination rows (permuted): j = pass*32 + r8i ->
  //   p32 = j&31 -> p = (c=bit2)*16 + (q=bits3-4)*4 + (r=bits0-1)
  int prow[2];
#pragma unroll
  for (int pass = 0; pass < 2; ++pass) {
    int jo = pass * 32 + r8i;
    int p32 = jo & 31;
    prow[pass] = (jo & 32) | ((p32 & 4) << 2) | (((p32 >> 3) & 3) << 2) | (p32 & 3);
  }

  int4 kreg[2], vreg[2];
#pragma unroll
  for (int pass = 0; pass < 2; ++pass) {
    kreg[pass] = *reinterpret_cast<const int4*>(
        kg + (size_t)(pass * 32 + r8i) * kC + seg * 8);
    vreg[pass] = *reinterpret_cast<const int4*>(
        vg + (size_t)(pass * 32 + r8i) * kS + seg * 8);
  }
#pragma unroll
  for (int pass = 0; pass < 2; ++pass) {
    *reinterpret_cast<int4*>(&Kt[0][prow[pass]][seg * 8]) = kreg[pass];
    *reinterpret_cast<int4*>(&Vt[0][pass * 32 + r8i][seg * 8]) = vreg[pass];
  }
  __syncthreads();

  f32x4 U[4][4];   // [h][dtile]: lane holds d=dtile*16+quad*4+reg, i=l16
#pragma unroll
  for (int h = 0; h < 4; ++h)
#pragma unroll
    for (int d = 0; d < 4; ++d) U[h][d] = zc;
  float lh[4] = {0.f, 0.f, 0.f, 0.f};

  for (int jt = 0; jt < kS / 64; ++jt) {
    const int buf = jt & 1;
    const bool more = (jt + 1) < kS / 64;
    if (more) {
      const int jn = (jt + 1) * 64;
#pragma unroll
      for (int pass = 0; pass < 2; ++pass) {
        kreg[pass] = *reinterpret_cast<const int4*>(
            kg + (size_t)(jn + pass * 32 + r8i) * kC + seg * 8);
        vreg[pass] = *reinterpret_cast<const int4*>(
            vg + (size_t)(pass * 32 + r8i) * kS + jn + seg * 8);
      }
    }

    // K A-frags (permuted rows): [chunk][window]; V^T A-frags per dtile
    short8 kf[2][2];
#pragma unroll
    for (int c = 0; c < 2; ++c)
#pragma unroll
      for (int w = 0; w < 2; ++w)
        kf[c][w] = *reinterpret_cast<const short8*>(
            &Kt[buf][jbase + c * 16 + l16][w * 32 + quad * 8]);
    short8 vf[4];
#pragma unroll
    for (int d = 0; d < 4; ++d)
      vf[d] = *reinterpret_cast<const short8*>(
          &Vt[buf][d * 16 + l16][jbase + quad * 8]);

#pragma unroll
    for (int h = 0; h < 4; ++h) {
      const int w = h >> 1;
      // chunk c result reg r = e(i=l16, j = quad*8 + c*4 + r)  [permutation]
      f32x4 s0 = __builtin_amdgcn_mfma_f32_16x16x32_bf16(kf[0][w], qm[h], zc, 0, 0, 0);
      f32x4 s1 = __builtin_amdgcn_mfma_f32_16x16x32_bf16(kf[1][w], qm[h], zc, 0, 0, 0);
      float e0 = __expf(s0[0]), e1 = __expf(s0[1]);
      float e2 = __expf(s0[2]), e3 = __expf(s0[3]);
      float f0 = __expf(s1[0]), f1 = __expf(s1[1]);
      float f2 = __expf(s1[2]), f3 = __expf(s1[3]);
      lh[h] += ((e0 + e1) + (e2 + e3)) + ((f0 + f1) + (f2 + f3));
      // pack: pf[idx] = e(i=l16, j=quad*8+idx) == PV B-frag, no LDS round-trip
      union { __hip_bfloat162 h2[4]; short8 s8; } cv;
      cv.h2[0] = __float22bfloat162_rn(make_float2(e0, e1));
      cv.h2[1] = __float22bfloat162_rn(make_float2(e2, e3));
      cv.h2[2] = __float22bfloat162_rn(make_float2(f0, f1));
      cv.h2[3] = __float22bfloat162_rn(make_float2(f2, f3));
#pragma unroll
      for (int d = 0; d < 4; ++d)
        U[h][d] = __builtin_amdgcn_mfma_f32_16x16x32_bf16(vf[d], cv.s8, U[h][d], 0, 0, 0);
    }

    if (more) {
      const int nb = buf ^ 1;
#pragma unroll
      for (int pass = 0; pass < 2; ++pass) {
        *reinterpret_cast<int4*>(&Kt[nb][prow[pass]][seg * 8]) = kreg[pass];
        *reinterpret_cast<int4*>(&Vt[nb][pass * 32 + r8i][seg * 8]) = vreg[pass];
      }
    }
    __syncthreads();
  }

  // ---- epilogue ----
#pragma unroll
  for (int h = 0; h < 4; ++h) {
    lh[h] += __shfl_xor(lh[h], 16, 64);
    lh[h] += __shfl_xor(lh[h], 32, 64);
  }
  if (quad == 0) {
#pragma unroll
    for (int h = 0; h < 4; ++h) pl[ws][l16][h] = lh[h];
  }
  __syncthreads();
  if (t < 128) {
    const int i = t >> 2, h = t & 3;    // i 0..31 (global sub-row)
    Li[i][h] = 0.25f / (pl[i >> 4][i & 15][h] + pl[(i >> 4) + 2][i & 15][h]);
  }
  __syncthreads();
  float c[4];
#pragma unroll
  for (int h = 0; h < 4; ++h) c[h] = Li[isub * 16 + l16][h];

  // jhalf-pair reduce, one d-tile per phase; slab lane-major (stride 66)
#pragma unroll
  for (int d = 0; d < 4; ++d) {
    if (jhalf == 1) {
#pragma unroll
      for (int h = 0; h < 4; ++h)
#pragma unroll
        for (int reg = 0; reg < 4; ++reg)
          slabF[((isub * 4 + h) * 4 + reg) * 66 + L] = U[h][d][reg];
    }
    __syncthreads();
    if (jhalf == 0) {
      float of[4] = {0.f, 0.f, 0.f, 0.f};
#pragma unroll
      for (int h = 0; h < 4; ++h) {
#pragma unroll
        for (int reg = 0; reg < 4; ++reg) {
          float tot = U[h][d][reg] + slabF[((isub * 4 + h) * 4 + reg) * 66 + L];
          of[reg] += tot * c[h];
        }
      }
      *reinterpret_cast<float4*>(
          out + ((size_t)b * kS + i0 + isub * 16 + l16) * kC + d * 16 + quad * 4) =
          make_float4(of[0], of[1], of[2], of[3]);
    }
    __syncthreads();
  }
}

// ---------------------------------------------------------------------------
extern "C" void kernel_launch(void* const* d_in, const int* in_sizes, int n_in,
                              void* d_out, int out_size, void* d_ws, size_t ws_size,
                              hipStream_t stream) {
  const float* q      = (const float*)d_in[0];
  const float* k      = (const float*)d_in[1];
  const float* v      = (const float*)d_in[2];
  const float* conv_w = (const float*)d_in[3];
  const float* nq_w   = (const float*)d_in[4];
  const float* nk_w   = (const float*)d_in[5];
  const float* wq     = (const float*)d_in[6];
  const float* bq     = (const float*)d_in[7];
  const float* wk     = (const float*)d_in[8];
  const float* bk     = (const float*)d_in[9];
  float* out = (float*)d_out;

  const size_t N = (size_t)kB * kS * kC;   // 1,179,648
  short* qt   = (short*)d_ws;     // bf16 [b][s][c]
  short* kt   = qt + N;
  short* vt   = kt + N;           // bf16 [b][c][s]
  short* qp   = vt + N;           // bf16 [b][s][64]
  short* kp   = qp + N;
  short* wqb3 = kp + N;           // frag-major bf16
  short* wkb3 = wqb3 + 4096;
  short* wt3  = wkb3 + 4096;      // frag-major bf16 [72 slabs][512]

  fused_prep<<<1904, 256, 0, stream>>>(q, k, v, wq, wk, conv_w,
                                       qt, kt, vt, wqb3, wkb3, wt3);
  fused_qk_gemm<<<576, 256, 0, stream>>>(qt, kt, wt3, wqb3, wkb3,
                                         nq_w, nk_w, bq, bk, qp, kp);
  attn_flash<<<576, 256, 0, stream>>>(qp, kp, vt, out);
}